// Round 1
// baseline (1527.535 us; speedup 1.0000x reference)
//
#include <hip/hip_runtime.h>
#include <hip/hip_bf16.h>

#define NN 100000
#define NE 1600000
#define NG 256
#define FIN 100
#define HH 64

__device__ __forceinline__ float relu_f(float x){ return x > 0.f ? x : 0.f; }

// ---------------- degree + dinv ----------------
__global__ void k_deg(const int* __restrict__ dst, int* __restrict__ deg) {
    int i = blockIdx.x * blockDim.x + threadIdx.x;
    int stride = gridDim.x * blockDim.x;
    for (; i < NE; i += stride) atomicAdd(&deg[dst[i]], 1);
}

__global__ void k_dinv(const int* __restrict__ deg, float* __restrict__ dinv) {
    int i = blockIdx.x * blockDim.x + threadIdx.x;
    if (i < NN) dinv[i] = rsqrtf((float)(deg[i] + 1));   // +1 self-loop, always >=1
}

// ---------------- embed: h = relu(x @ W_emb + b) ----------------
__global__ __launch_bounds__(256) void k_embed(const float* __restrict__ x,
                                               const float* __restrict__ Wemb,
                                               const float* __restrict__ bemb,
                                               float* __restrict__ h) {
    __shared__ __align__(16) float Wl[FIN * HH];   // 25.6 KB
    __shared__ __align__(16) float Xl[64 * FIN];   // 25.6 KB
    int tid = threadIdx.x;
    for (int i = tid; i < FIN * HH; i += 256) Wl[i] = Wemb[i];
    int row0 = blockIdx.x * 64;
    const float* xs = x + (size_t)row0 * FIN;
    int lim = (NN - row0 < 64 ? NN - row0 : 64) * FIN;
    for (int i = tid; i < 64 * FIN; i += 256) Xl[i] = (i < lim) ? xs[i] : 0.f;
    __syncthreads();

    int wave = tid >> 6, lane = tid & 63;
    int rbase = wave * 16;
    float acc[16];
    #pragma unroll
    for (int r = 0; r < 16; ++r) acc[r] = 0.f;

    for (int k = 0; k < FIN; k += 4) {
        float w0 = Wl[(k+0)*HH + lane];
        float w1 = Wl[(k+1)*HH + lane];
        float w2 = Wl[(k+2)*HH + lane];
        float w3 = Wl[(k+3)*HH + lane];
        #pragma unroll
        for (int r = 0; r < 16; ++r) {
            const float4 xv = *reinterpret_cast<const float4*>(&Xl[(rbase + r) * FIN + k]);
            acc[r] = fmaf(xv.x, w0, acc[r]);
            acc[r] = fmaf(xv.y, w1, acc[r]);
            acc[r] = fmaf(xv.z, w2, acc[r]);
            acc[r] = fmaf(xv.w, w3, acc[r]);
        }
    }
    float b = bemb[lane];
    #pragma unroll
    for (int r = 0; r < 16; ++r) {
        int row = row0 + rbase + r;
        if (row < NN) h[(size_t)row * HH + lane] = relu_f(acc[r] + b);
    }
}

// ---------------- per-layer GEMM: g = dinv * (T(X) @ W), acc_out = g ----------------
// MODE 0: T(x) = x (input already activated)
// MODE 1: T(x) = relu(dinv[row]*x + bprev[k])   (fused finalize of previous layer)
template <int MODE>
__global__ __launch_bounds__(256) void k_gemm64(const float* __restrict__ X,
                                                const float* __restrict__ W,
                                                const float* __restrict__ bprev,
                                                const float* __restrict__ dinv,
                                                float* __restrict__ g,
                                                float* __restrict__ acc_out) {
    __shared__ __align__(16) float Wl[HH * HH];   // 16 KB
    __shared__ __align__(16) float Xl[64 * HH];   // 16 KB
    int tid = threadIdx.x;
    for (int i = tid; i < HH * HH; i += 256) Wl[i] = W[i];
    int row0 = blockIdx.x * 64;
    for (int i = tid; i < 64 * HH; i += 256) {
        int r = i >> 6, k = i & 63;
        int row = row0 + r;
        float v = 0.f;
        if (row < NN) {
            v = X[(size_t)row * HH + k];
            if (MODE == 1) v = relu_f(dinv[row] * v + bprev[k]);
        }
        Xl[i] = v;
    }
    __syncthreads();

    int wave = tid >> 6, lane = tid & 63;
    int rbase = wave * 16;
    float acc[16];
    #pragma unroll
    for (int r = 0; r < 16; ++r) acc[r] = 0.f;

    for (int k = 0; k < HH; k += 4) {
        float w0 = Wl[(k+0)*HH + lane];
        float w1 = Wl[(k+1)*HH + lane];
        float w2 = Wl[(k+2)*HH + lane];
        float w3 = Wl[(k+3)*HH + lane];
        #pragma unroll
        for (int r = 0; r < 16; ++r) {
            const float4 xv = *reinterpret_cast<const float4*>(&Xl[(rbase + r) * HH + k]);
            acc[r] = fmaf(xv.x, w0, acc[r]);
            acc[r] = fmaf(xv.y, w1, acc[r]);
            acc[r] = fmaf(xv.z, w2, acc[r]);
            acc[r] = fmaf(xv.w, w3, acc[r]);
        }
    }
    #pragma unroll
    for (int r = 0; r < 16; ++r) {
        int row = row0 + rbase + r;
        if (row < NN) {
            float val = dinv[row] * acc[r];
            g[(size_t)row * HH + lane] = val;        // message source
            acc_out[(size_t)row * HH + lane] = val;  // self-loop init of accumulator
        }
    }
}

// ---------------- scatter: acc[dst] += g[src], one wave per edge ----------------
__global__ __launch_bounds__(256) void k_scatter(const int* __restrict__ src,
                                                 const int* __restrict__ dst,
                                                 const float* __restrict__ g,
                                                 float* __restrict__ acc) {
    int lane = threadIdx.x & 63;
    int wid = (blockIdx.x * blockDim.x + threadIdx.x) >> 6;
    int nw = (gridDim.x * blockDim.x) >> 6;
    for (int e = wid; e < NE; e += nw) {
        int s = src[e], d = dst[e];
        float v = g[(size_t)s * HH + lane];
        unsafeAtomicAdd(&acc[(size_t)d * HH + lane], v);
    }
}

// ---------------- pool: pooled[batch[n]] += relu(dinv*acc + bL); cnt ----------------
__global__ __launch_bounds__(256) void k_pool(const float* __restrict__ acc,
                                              const float* __restrict__ dinv,
                                              const float* __restrict__ bL,
                                              const int* __restrict__ batch,
                                              float* __restrict__ pooled,
                                              int* __restrict__ cnt) {
    int lane = threadIdx.x & 63;
    int wid = (blockIdx.x * blockDim.x + threadIdx.x) >> 6;
    int nw = (gridDim.x * blockDim.x) >> 6;
    float b = bL[lane];
    for (int n = wid; n < NN; n += nw) {
        float v = relu_f(dinv[n] * acc[(size_t)n * HH + lane] + b);
        int gi = batch[n];
        unsafeAtomicAdd(&pooled[gi * HH + lane], v);
        if (lane == 0) atomicAdd(&cnt[gi], 1);
    }
}

// ---------------- MLP readout: 1 block, thread = graph ----------------
__global__ __launch_bounds__(256) void k_mlp(const float* __restrict__ pooled,
                                             const int* __restrict__ cnt,
                                             const float* __restrict__ W1, const float* __restrict__ b1,
                                             const float* __restrict__ W2, const float* __restrict__ b2,
                                             const float* __restrict__ W3, const float* __restrict__ b3,
                                             float* __restrict__ out) {
    __shared__ float W1l[64 * 64];
    __shared__ float W2l[64 * 32];
    __shared__ float W3l[32];
    __shared__ float b1l[64];
    __shared__ float b2l[32];
    int tid = threadIdx.x;
    for (int i = tid; i < 4096; i += 256) W1l[i] = W1[i];
    for (int i = tid; i < 2048; i += 256) W2l[i] = W2[i];
    if (tid < 32) W3l[tid] = W3[tid];
    if (tid < 64) b1l[tid] = b1[tid];
    if (tid < 32) b2l[tid] = b2[tid];
    __syncthreads();

    int g = tid;
    float inv = 1.f / (float)max(cnt[g], 1);
    float p[64];
    #pragma unroll
    for (int k = 0; k < 64; ++k) p[k] = pooled[g * 64 + k] * inv;
    float t[64];
    #pragma unroll
    for (int j = 0; j < 64; ++j) {
        float s = b1l[j];
        #pragma unroll
        for (int k = 0; k < 64; ++k) s = fmaf(p[k], W1l[k * 64 + j], s);
        t[j] = relu_f(s);
    }
    float q[32];
    #pragma unroll
    for (int j = 0; j < 32; ++j) {
        float s = b2l[j];
        #pragma unroll
        for (int k = 0; k < 64; ++k) s = fmaf(t[k], W2l[k * 32 + j], s);
        q[j] = relu_f(s);
    }
    float s = b3[0];
    #pragma unroll
    for (int k = 0; k < 32; ++k) s = fmaf(q[k], W3l[k], s);
    out[g] = s;
}

extern "C" void kernel_launch(void* const* d_in, const int* in_sizes, int n_in,
                              void* d_out, int out_size, void* d_ws, size_t ws_size,
                              hipStream_t stream) {
    const float* x    = (const float*)d_in[0];
    const int*   ei   = (const int*)d_in[1];
    const int*   batch= (const int*)d_in[2];
    const float* Wemb = (const float*)d_in[3];
    const float* bemb = (const float*)d_in[4];
    const float* convW= (const float*)d_in[5];
    const float* convb= (const float*)d_in[6];
    const float* W1   = (const float*)d_in[7];
    const float* b1   = (const float*)d_in[8];
    const float* W2   = (const float*)d_in[9];
    const float* b2   = (const float*)d_in[10];
    const float* W3   = (const float*)d_in[11];
    const float* b3   = (const float*)d_in[12];
    float* out = (float*)d_out;

    char* ws = (char*)d_ws;
    int*   deg  = (int*)ws;                                    // N ints
    float* dinv = (float*)(ws + (size_t)NN * 4);               // N floats
    float* buf0 = (float*)(ws + (size_t)2 * NN * 4);           // N*64
    float* buf1 = buf0 + (size_t)NN * HH;                      // N*64
    float* buf2 = buf1 + (size_t)NN * HH;                      // N*64
    float* pooled = buf2 + (size_t)NN * HH;                    // G*64
    int*   cnt  = (int*)(pooled + NG * HH);                    // G ints

    const int* srcA = ei;
    const int* dstA = ei + NE;

    hipMemsetAsync(deg, 0, (size_t)NN * 4, stream);
    hipMemsetAsync(pooled, 0, (size_t)(NG * HH) * 4 + NG * 4, stream);

    k_deg<<<1024, 256, 0, stream>>>(dstA, deg);
    k_dinv<<<(NN + 255) / 256, 256, 0, stream>>>(deg, dinv);
    k_embed<<<(NN + 63) / 64, 256, 0, stream>>>(x, Wemb, bemb, buf0);

    int gblk = (NN + 63) / 64;
    // layer 0: X=buf0 (raw) -> g=buf1, acc=buf2
    k_gemm64<0><<<gblk, 256, 0, stream>>>(buf0, convW + 0 * HH * HH, nullptr, dinv, buf1, buf2);
    k_scatter<<<2048, 256, 0, stream>>>(srcA, dstA, buf1, buf2);
    // layer 1: X=buf2 (relu(dinv*x+b0)) -> g=buf1, acc=buf0
    k_gemm64<1><<<gblk, 256, 0, stream>>>(buf2, convW + 1 * HH * HH, convb + 0 * HH, dinv, buf1, buf0);
    k_scatter<<<2048, 256, 0, stream>>>(srcA, dstA, buf1, buf0);
    // layer 2: X=buf0 (relu(dinv*x+b1)) -> g=buf1, acc=buf2
    k_gemm64<1><<<gblk, 256, 0, stream>>>(buf0, convW + 2 * HH * HH, convb + 1 * HH, dinv, buf1, buf2);
    k_scatter<<<2048, 256, 0, stream>>>(srcA, dstA, buf1, buf2);

    // pool (finalize layer 2 with b=convb[2]) + counts
    k_pool<<<2048, 256, 0, stream>>>(buf2, dinv, convb + 2 * HH, batch, pooled, cnt);
    // MLP readout
    k_mlp<<<1, 256, 0, stream>>>(pooled, cnt, W1, b1, W2, b2, W3, b3, out);
}

// Round 2
// 833.039 us; speedup vs baseline: 1.8337x; 1.8337x over previous
//
#include <hip/hip_runtime.h>
#include <hip/hip_bf16.h>

#define NN 100000
#define NE 1600000
#define NG 256
#define FIN 100
#define HH 64
#define NB 98   // scan blocks: 98 * 1024 >= NN

__device__ __forceinline__ float relu_f(float x){ return x > 0.f ? x : 0.f; }

// ---------------- degree histogram ----------------
__global__ void k_deg(const int* __restrict__ dst, int* __restrict__ deg) {
    int i = blockIdx.x * blockDim.x + threadIdx.x;
    int stride = gridDim.x * blockDim.x;
    for (; i < NE; i += stride) atomicAdd(&deg[dst[i]], 1);
}

__global__ void k_dinv(const int* __restrict__ deg, float* __restrict__ dinv) {
    int i = blockIdx.x * blockDim.x + threadIdx.x;
    if (i < NN) dinv[i] = rsqrtf((float)(deg[i] + 1));   // +1 self-loop
}

// ---------------- 2-level exclusive scan of deg -> row_start, cursor ----------------
__global__ __launch_bounds__(256) void k_scan_part(const int* __restrict__ deg,
                                                   int* __restrict__ blockSums) {
    int b = blockIdx.x, t = threadIdx.x;
    int i0 = b * 1024 + t * 4;
    int s = 0;
    #pragma unroll
    for (int j = 0; j < 4; ++j) { int i = i0 + j; s += (i < NN) ? deg[i] : 0; }
    __shared__ int lds[256];
    lds[t] = s; __syncthreads();
    for (int off = 128; off > 0; off >>= 1) {
        if (t < off) lds[t] += lds[t + off];
        __syncthreads();
    }
    if (t == 0) blockSums[b] = lds[0];
}

__global__ void k_scan_sums(int* __restrict__ blockSums) {
    if (threadIdx.x == 0 && blockIdx.x == 0) {
        int run = 0;
        for (int i = 0; i < NB; ++i) { int v = blockSums[i]; blockSums[i] = run; run += v; }
    }
}

__global__ __launch_bounds__(256) void k_scan_final(const int* __restrict__ deg,
                                                    const int* __restrict__ blockSums,
                                                    int* __restrict__ row_start,
                                                    int* __restrict__ cursor) {
    int b = blockIdx.x, t = threadIdx.x;
    int i0 = b * 1024 + t * 4;
    int v[4]; int s = 0;
    #pragma unroll
    for (int j = 0; j < 4; ++j) { int i = i0 + j; v[j] = (i < NN) ? deg[i] : 0; s += v[j]; }
    int lane = t & 63, wave = t >> 6;
    int inc = s;
    for (int off = 1; off < 64; off <<= 1) {
        int n = __shfl_up(inc, off, 64);
        if (lane >= off) inc += n;
    }
    __shared__ int wsum[4];
    if (lane == 63) wsum[wave] = inc;
    __syncthreads();
    int woff = 0;
    for (int w = 0; w < wave; ++w) woff += wsum[w];
    int excl = blockSums[b] + woff + (inc - s);
    #pragma unroll
    for (int j = 0; j < 4; ++j) {
        int i = i0 + j;
        if (i < NN) { row_start[i] = excl; cursor[i] = excl; }
        excl += v[j];
    }
}

// ---------------- place edges into CSR by dst ----------------
__global__ void k_place(const int* __restrict__ src, const int* __restrict__ dst,
                        int* __restrict__ cursor, int* __restrict__ csr_src) {
    int i = blockIdx.x * blockDim.x + threadIdx.x;
    int stride = gridDim.x * blockDim.x;
    for (; i < NE; i += stride) {
        int d = dst[i];
        int pos = atomicAdd(&cursor[d], 1);
        csr_src[pos] = src[i];
    }
}

// ---------------- embed: h = relu(x @ W_emb + b) ----------------
__global__ __launch_bounds__(256) void k_embed(const float* __restrict__ x,
                                               const float* __restrict__ Wemb,
                                               const float* __restrict__ bemb,
                                               float* __restrict__ h) {
    __shared__ __align__(16) float Wl[FIN * HH];
    __shared__ __align__(16) float Xl[64 * FIN];
    int tid = threadIdx.x;
    for (int i = tid; i < FIN * HH; i += 256) Wl[i] = Wemb[i];
    int row0 = blockIdx.x * 64;
    const float* xs = x + (size_t)row0 * FIN;
    int lim = (NN - row0 < 64 ? NN - row0 : 64) * FIN;
    for (int i = tid; i < 64 * FIN; i += 256) Xl[i] = (i < lim) ? xs[i] : 0.f;
    __syncthreads();

    int wave = tid >> 6, lane = tid & 63;
    int rbase = wave * 16;
    float acc[16];
    #pragma unroll
    for (int r = 0; r < 16; ++r) acc[r] = 0.f;

    for (int k = 0; k < FIN; k += 4) {
        float w0 = Wl[(k+0)*HH + lane];
        float w1 = Wl[(k+1)*HH + lane];
        float w2 = Wl[(k+2)*HH + lane];
        float w3 = Wl[(k+3)*HH + lane];
        #pragma unroll
        for (int r = 0; r < 16; ++r) {
            const float4 xv = *reinterpret_cast<const float4*>(&Xl[(rbase + r) * FIN + k]);
            acc[r] = fmaf(xv.x, w0, acc[r]);
            acc[r] = fmaf(xv.y, w1, acc[r]);
            acc[r] = fmaf(xv.z, w2, acc[r]);
            acc[r] = fmaf(xv.w, w3, acc[r]);
        }
    }
    float b = bemb[lane];
    #pragma unroll
    for (int r = 0; r < 16; ++r) {
        int row = row0 + rbase + r;
        if (row < NN) h[(size_t)row * HH + lane] = relu_f(acc[r] + b);
    }
}

// ---------------- per-layer GEMM: g = dinv * (T(X) @ W) ----------------
// MODE 0: T(x) = x; MODE 1: T(x) = relu(dinv[row]*x + bprev[k])
template <int MODE>
__global__ __launch_bounds__(256) void k_gemm64(const float* __restrict__ X,
                                                const float* __restrict__ W,
                                                const float* __restrict__ bprev,
                                                const float* __restrict__ dinv,
                                                float* __restrict__ g) {
    __shared__ __align__(16) float Wl[HH * HH];
    __shared__ __align__(16) float Xl[64 * HH];
    int tid = threadIdx.x;
    for (int i = tid; i < HH * HH; i += 256) Wl[i] = W[i];
    int row0 = blockIdx.x * 64;
    for (int i = tid; i < 64 * HH; i += 256) {
        int r = i >> 6, k = i & 63;
        int row = row0 + r;
        float v = 0.f;
        if (row < NN) {
            v = X[(size_t)row * HH + k];
            if (MODE == 1) v = relu_f(dinv[row] * v + bprev[k]);
        }
        Xl[i] = v;
    }
    __syncthreads();

    int wave = tid >> 6, lane = tid & 63;
    int rbase = wave * 16;
    float acc[16];
    #pragma unroll
    for (int r = 0; r < 16; ++r) acc[r] = 0.f;

    for (int k = 0; k < HH; k += 4) {
        float w0 = Wl[(k+0)*HH + lane];
        float w1 = Wl[(k+1)*HH + lane];
        float w2 = Wl[(k+2)*HH + lane];
        float w3 = Wl[(k+3)*HH + lane];
        #pragma unroll
        for (int r = 0; r < 16; ++r) {
            const float4 xv = *reinterpret_cast<const float4*>(&Xl[(rbase + r) * HH + k]);
            acc[r] = fmaf(xv.x, w0, acc[r]);
            acc[r] = fmaf(xv.y, w1, acc[r]);
            acc[r] = fmaf(xv.z, w2, acc[r]);
            acc[r] = fmaf(xv.w, w3, acc[r]);
        }
    }
    #pragma unroll
    for (int r = 0; r < 16; ++r) {
        int row = row0 + rbase + r;
        if (row < NN) g[(size_t)row * HH + lane] = dinv[row] * acc[r];
    }
}

// ---------------- CSR aggregate: out[v] = g[v] + sum_{e in in(v)} g[src[e]] ----------------
__global__ __launch_bounds__(256) void k_agg(const int* __restrict__ row_start,
                                             const int* __restrict__ deg,
                                             const int* __restrict__ csr_src,
                                             const float* __restrict__ g,
                                             float* __restrict__ out) {
    int lane = threadIdx.x & 63;
    int wave = threadIdx.x >> 6;
    int v = blockIdx.x * 4 + wave;
    if (v >= NN) return;
    int start = row_start[v];
    int n = deg[v];
    float acc = g[(size_t)v * HH + lane];          // self loop
    for (int base = 0; base < n; base += 64) {
        int m = n - base; if (m > 64) m = 64;
        int sv = (lane < m) ? csr_src[start + base + lane] : 0;
        int j = 0;
        for (; j + 4 <= m; j += 4) {
            int s0 = __shfl(sv, j), s1 = __shfl(sv, j + 1);
            int s2 = __shfl(sv, j + 2), s3 = __shfl(sv, j + 3);
            float a0 = g[(size_t)s0 * HH + lane];
            float a1 = g[(size_t)s1 * HH + lane];
            float a2 = g[(size_t)s2 * HH + lane];
            float a3 = g[(size_t)s3 * HH + lane];
            acc += a0; acc += a1; acc += a2; acc += a3;
        }
        for (; j < m; ++j) {
            int s = __shfl(sv, j);
            acc += g[(size_t)s * HH + lane];
        }
    }
    out[(size_t)v * HH + lane] = acc;
}

// ---------------- pool ----------------
__global__ __launch_bounds__(256) void k_pool(const float* __restrict__ acc,
                                              const float* __restrict__ dinv,
                                              const float* __restrict__ bL,
                                              const int* __restrict__ batch,
                                              float* __restrict__ pooled,
                                              int* __restrict__ cnt) {
    int lane = threadIdx.x & 63;
    int wid = (blockIdx.x * blockDim.x + threadIdx.x) >> 6;
    int nw = (gridDim.x * blockDim.x) >> 6;
    float b = bL[lane];
    for (int n = wid; n < NN; n += nw) {
        float v = relu_f(dinv[n] * acc[(size_t)n * HH + lane] + b);
        int gi = batch[n];
        unsafeAtomicAdd(&pooled[gi * HH + lane], v);
        if (lane == 0) atomicAdd(&cnt[gi], 1);
    }
}

// ---------------- MLP readout ----------------
__global__ __launch_bounds__(256) void k_mlp(const float* __restrict__ pooled,
                                             const int* __restrict__ cnt,
                                             const float* __restrict__ W1, const float* __restrict__ b1,
                                             const float* __restrict__ W2, const float* __restrict__ b2,
                                             const float* __restrict__ W3, const float* __restrict__ b3,
                                             float* __restrict__ out) {
    __shared__ float W1l[64 * 64];
    __shared__ float W2l[64 * 32];
    __shared__ float W3l[32];
    __shared__ float b1l[64];
    __shared__ float b2l[32];
    int tid = threadIdx.x;
    for (int i = tid; i < 4096; i += 256) W1l[i] = W1[i];
    for (int i = tid; i < 2048; i += 256) W2l[i] = W2[i];
    if (tid < 32) W3l[tid] = W3[tid];
    if (tid < 64) b1l[tid] = b1[tid];
    if (tid < 32) b2l[tid] = b2[tid];
    __syncthreads();

    int g = tid;
    float inv = 1.f / (float)max(cnt[g], 1);
    float p[64];
    #pragma unroll
    for (int k = 0; k < 64; ++k) p[k] = pooled[g * 64 + k] * inv;
    float t[64];
    #pragma unroll
    for (int j = 0; j < 64; ++j) {
        float s = b1l[j];
        #pragma unroll
        for (int k = 0; k < 64; ++k) s = fmaf(p[k], W1l[k * 64 + j], s);
        t[j] = relu_f(s);
    }
    float q[32];
    #pragma unroll
    for (int j = 0; j < 32; ++j) {
        float s = b2l[j];
        #pragma unroll
        for (int k = 0; k < 64; ++k) s = fmaf(t[k], W2l[k * 32 + j], s);
        q[j] = relu_f(s);
    }
    float s = b3[0];
    #pragma unroll
    for (int k = 0; k < 32; ++k) s = fmaf(q[k], W3l[k], s);
    out[g] = s;
}

extern "C" void kernel_launch(void* const* d_in, const int* in_sizes, int n_in,
                              void* d_out, int out_size, void* d_ws, size_t ws_size,
                              hipStream_t stream) {
    const float* x    = (const float*)d_in[0];
    const int*   ei   = (const int*)d_in[1];
    const int*   batch= (const int*)d_in[2];
    const float* Wemb = (const float*)d_in[3];
    const float* bemb = (const float*)d_in[4];
    const float* convW= (const float*)d_in[5];
    const float* convb= (const float*)d_in[6];
    const float* W1   = (const float*)d_in[7];
    const float* b1   = (const float*)d_in[8];
    const float* W2   = (const float*)d_in[9];
    const float* b2   = (const float*)d_in[10];
    const float* W3   = (const float*)d_in[11];
    const float* b3   = (const float*)d_in[12];
    float* out = (float*)d_out;

    char* ws = (char*)d_ws;
    int*   deg       = (int*)ws;                         // N
    float* dinv      = (float*)(deg + NN);               // N
    int*   row_start = (int*)(dinv + NN);                // N
    int*   cursor    = row_start + NN;                   // N
    int*   blockSums = cursor + NN;                      // 128 (pad)
    int*   csr_src   = blockSums + 128;                  // E
    float* bufA      = (float*)(csr_src + NE);           // N*64
    float* bufB      = bufA + (size_t)NN * HH;           // N*64
    float* pooled    = bufB + (size_t)NN * HH;           // G*64
    int*   cnt       = (int*)(pooled + NG * HH);         // G

    const int* srcA = ei;
    const int* dstA = ei + NE;

    hipMemsetAsync(deg, 0, (size_t)NN * 4, stream);
    hipMemsetAsync(pooled, 0, (size_t)(NG * HH) * 4 + NG * 4, stream);

    k_deg<<<1024, 256, 0, stream>>>(dstA, deg);
    k_dinv<<<(NN + 255) / 256, 256, 0, stream>>>(deg, dinv);
    k_scan_part<<<NB, 256, 0, stream>>>(deg, blockSums);
    k_scan_sums<<<1, 64, 0, stream>>>(blockSums);
    k_scan_final<<<NB, 256, 0, stream>>>(deg, blockSums, row_start, cursor);
    k_place<<<2048, 256, 0, stream>>>(srcA, dstA, cursor, csr_src);

    k_embed<<<(NN + 63) / 64, 256, 0, stream>>>(x, Wemb, bemb, bufA);

    int gblk = (NN + 63) / 64;
    int ablk = (NN + 3) / 4;
    // layer 0
    k_gemm64<0><<<gblk, 256, 0, stream>>>(bufA, convW + 0 * HH * HH, nullptr, dinv, bufB);
    k_agg<<<ablk, 256, 0, stream>>>(row_start, deg, csr_src, bufB, bufA);
    // layer 1
    k_gemm64<1><<<gblk, 256, 0, stream>>>(bufA, convW + 1 * HH * HH, convb + 0 * HH, dinv, bufB);
    k_agg<<<ablk, 256, 0, stream>>>(row_start, deg, csr_src, bufB, bufA);
    // layer 2
    k_gemm64<1><<<gblk, 256, 0, stream>>>(bufA, convW + 2 * HH * HH, convb + 1 * HH, dinv, bufB);
    k_agg<<<ablk, 256, 0, stream>>>(row_start, deg, csr_src, bufB, bufA);

    k_pool<<<2048, 256, 0, stream>>>(bufA, dinv, convb + 2 * HH, batch, pooled, cnt);
    k_mlp<<<1, 256, 0, stream>>>(pooled, cnt, W1, b1, W2, b2, W3, b3, out);
}

// Round 3
// 600.636 us; speedup vs baseline: 2.5432x; 1.3869x over previous
//
#include <hip/hip_runtime.h>
#include <hip/hip_bf16.h>

#define NN 100000
#define NE 1600000
#define NG 256
#define FIN 100
#define HH 64
#define NB 98   // scan blocks: 98 * 1024 >= NN

__device__ __forceinline__ float relu_f(float x){ return x > 0.f ? x : 0.f; }

// ---------------- degree histogram ----------------
__global__ void k_deg(const int* __restrict__ dst, int* __restrict__ deg) {
    int i = blockIdx.x * blockDim.x + threadIdx.x;
    int stride = gridDim.x * blockDim.x;
    for (; i < NE; i += stride) atomicAdd(&deg[dst[i]], 1);
}

__global__ void k_dinv(const int* __restrict__ deg, float* __restrict__ dinv) {
    int i = blockIdx.x * blockDim.x + threadIdx.x;
    if (i < NN) dinv[i] = rsqrtf((float)(deg[i] + 1));   // +1 self-loop
}

// ---------------- 2-level exclusive scan of deg -> row_start, cursor ----------------
__global__ __launch_bounds__(256) void k_scan_part(const int* __restrict__ deg,
                                                   int* __restrict__ blockSums) {
    int b = blockIdx.x, t = threadIdx.x;
    int i0 = b * 1024 + t * 4;
    int s = 0;
    #pragma unroll
    for (int j = 0; j < 4; ++j) { int i = i0 + j; s += (i < NN) ? deg[i] : 0; }
    __shared__ int lds[256];
    lds[t] = s; __syncthreads();
    for (int off = 128; off > 0; off >>= 1) {
        if (t < off) lds[t] += lds[t + off];
        __syncthreads();
    }
    if (t == 0) blockSums[b] = lds[0];
}

__global__ void k_scan_sums(int* __restrict__ blockSums) {
    if (threadIdx.x == 0 && blockIdx.x == 0) {
        int run = 0;
        for (int i = 0; i < NB; ++i) { int v = blockSums[i]; blockSums[i] = run; run += v; }
    }
}

__global__ __launch_bounds__(256) void k_scan_final(const int* __restrict__ deg,
                                                    const int* __restrict__ blockSums,
                                                    int* __restrict__ row_start,
                                                    int* __restrict__ cursor) {
    int b = blockIdx.x, t = threadIdx.x;
    int i0 = b * 1024 + t * 4;
    int v[4]; int s = 0;
    #pragma unroll
    for (int j = 0; j < 4; ++j) { int i = i0 + j; v[j] = (i < NN) ? deg[i] : 0; s += v[j]; }
    int lane = t & 63, wave = t >> 6;
    int inc = s;
    for (int off = 1; off < 64; off <<= 1) {
        int n = __shfl_up(inc, off, 64);
        if (lane >= off) inc += n;
    }
    __shared__ int wsum[4];
    if (lane == 63) wsum[wave] = inc;
    __syncthreads();
    int woff = 0;
    for (int w = 0; w < wave; ++w) woff += wsum[w];
    int excl = blockSums[b] + woff + (inc - s);
    #pragma unroll
    for (int j = 0; j < 4; ++j) {
        int i = i0 + j;
        if (i < NN) { row_start[i] = excl; cursor[i] = excl; }
        excl += v[j];
    }
}

// ---------------- place edges into CSR by dst ----------------
__global__ void k_place(const int* __restrict__ src, const int* __restrict__ dst,
                        int* __restrict__ cursor, int* __restrict__ csr_src) {
    int i = blockIdx.x * blockDim.x + threadIdx.x;
    int stride = gridDim.x * blockDim.x;
    for (; i < NE; i += stride) {
        int d = dst[i];
        int pos = atomicAdd(&cursor[d], 1);
        csr_src[pos] = src[i];
    }
}

// ---------------- embed: h = relu(x @ W_emb + b) ----------------
__global__ __launch_bounds__(256) void k_embed(const float* __restrict__ x,
                                               const float* __restrict__ Wemb,
                                               const float* __restrict__ bemb,
                                               float* __restrict__ h) {
    __shared__ __align__(16) float Wl[FIN * HH];
    __shared__ __align__(16) float Xl[64 * FIN];
    int tid = threadIdx.x;
    for (int i = tid; i < FIN * HH; i += 256) Wl[i] = Wemb[i];
    int row0 = blockIdx.x * 64;
    const float* xs = x + (size_t)row0 * FIN;
    int lim = (NN - row0 < 64 ? NN - row0 : 64) * FIN;
    for (int i = tid; i < 64 * FIN; i += 256) Xl[i] = (i < lim) ? xs[i] : 0.f;
    __syncthreads();

    int wave = tid >> 6, lane = tid & 63;
    int rbase = wave * 16;
    float acc[16];
    #pragma unroll
    for (int r = 0; r < 16; ++r) acc[r] = 0.f;

    for (int k = 0; k < FIN; k += 4) {
        float w0 = Wl[(k+0)*HH + lane];
        float w1 = Wl[(k+1)*HH + lane];
        float w2 = Wl[(k+2)*HH + lane];
        float w3 = Wl[(k+3)*HH + lane];
        #pragma unroll
        for (int r = 0; r < 16; ++r) {
            const float4 xv = *reinterpret_cast<const float4*>(&Xl[(rbase + r) * FIN + k]);
            acc[r] = fmaf(xv.x, w0, acc[r]);
            acc[r] = fmaf(xv.y, w1, acc[r]);
            acc[r] = fmaf(xv.z, w2, acc[r]);
            acc[r] = fmaf(xv.w, w3, acc[r]);
        }
    }
    float b = bemb[lane];
    #pragma unroll
    for (int r = 0; r < 16; ++r) {
        int row = row0 + rbase + r;
        if (row < NN) h[(size_t)row * HH + lane] = relu_f(acc[r] + b);
    }
}

// ---------------- per-layer GEMM: g = dinv * (T(X) @ W) ----------------
// MODE 0: T(x) = x; MODE 1: T(x) = relu(dinv[row]*x + bprev[k])
template <int MODE>
__global__ __launch_bounds__(256) void k_gemm64(const float* __restrict__ X,
                                                const float* __restrict__ W,
                                                const float* __restrict__ bprev,
                                                const float* __restrict__ dinv,
                                                float* __restrict__ g) {
    __shared__ __align__(16) float Wl[HH * HH];
    __shared__ __align__(16) float Xl[64 * HH];
    int tid = threadIdx.x;
    for (int i = tid; i < HH * HH; i += 256) Wl[i] = W[i];
    int row0 = blockIdx.x * 64;
    for (int i = tid; i < 64 * HH; i += 256) {
        int r = i >> 6, k = i & 63;
        int row = row0 + r;
        float v = 0.f;
        if (row < NN) {
            v = X[(size_t)row * HH + k];
            if (MODE == 1) v = relu_f(dinv[row] * v + bprev[k]);
        }
        Xl[i] = v;
    }
    __syncthreads();

    int wave = tid >> 6, lane = tid & 63;
    int rbase = wave * 16;
    float acc[16];
    #pragma unroll
    for (int r = 0; r < 16; ++r) acc[r] = 0.f;

    for (int k = 0; k < HH; k += 4) {
        float w0 = Wl[(k+0)*HH + lane];
        float w1 = Wl[(k+1)*HH + lane];
        float w2 = Wl[(k+2)*HH + lane];
        float w3 = Wl[(k+3)*HH + lane];
        #pragma unroll
        for (int r = 0; r < 16; ++r) {
            const float4 xv = *reinterpret_cast<const float4*>(&Xl[(rbase + r) * HH + k]);
            acc[r] = fmaf(xv.x, w0, acc[r]);
            acc[r] = fmaf(xv.y, w1, acc[r]);
            acc[r] = fmaf(xv.z, w2, acc[r]);
            acc[r] = fmaf(xv.w, w3, acc[r]);
        }
    }
    #pragma unroll
    for (int r = 0; r < 16; ++r) {
        int row = row0 + rbase + r;
        if (row < NN) g[(size_t)row * HH + lane] = dinv[row] * acc[r];
    }
}

// ---------------- CSR aggregate: out[v] = g[v] + sum_{e in in(v)} g[src[e]] ----------------
__global__ __launch_bounds__(256) void k_agg(const int* __restrict__ row_start,
                                             const int* __restrict__ deg,
                                             const int* __restrict__ csr_src,
                                             const float* __restrict__ g,
                                             float* __restrict__ out) {
    int lane = threadIdx.x & 63;
    int wave = threadIdx.x >> 6;
    int v = blockIdx.x * 4 + wave;
    if (v >= NN) return;
    int start = row_start[v];
    int n = deg[v];
    float acc = g[(size_t)v * HH + lane];          // self loop
    for (int base = 0; base < n; base += 64) {
        int m = n - base; if (m > 64) m = 64;
        int sv = (lane < m) ? csr_src[start + base + lane] : 0;
        int j = 0;
        for (; j + 4 <= m; j += 4) {
            int s0 = __shfl(sv, j), s1 = __shfl(sv, j + 1);
            int s2 = __shfl(sv, j + 2), s3 = __shfl(sv, j + 3);
            float a0 = g[(size_t)s0 * HH + lane];
            float a1 = g[(size_t)s1 * HH + lane];
            float a2 = g[(size_t)s2 * HH + lane];
            float a3 = g[(size_t)s3 * HH + lane];
            acc += a0; acc += a1; acc += a2; acc += a3;
        }
        for (; j < m; ++j) {
            int s = __shfl(sv, j);
            acc += g[(size_t)s * HH + lane];
        }
    }
    out[(size_t)v * HH + lane] = acc;
}

// ---------------- fused pool + MLP: one block per graph, zero atomics ----------------
// batch is sorted, so graph g's nodes are a contiguous range [lo, hi).
__global__ __launch_bounds__(256) void k_pool_mlp(const float* __restrict__ acc,
                                                  const float* __restrict__ dinv,
                                                  const float* __restrict__ bL,
                                                  const int* __restrict__ batch,
                                                  const float* __restrict__ W1, const float* __restrict__ b1,
                                                  const float* __restrict__ W2, const float* __restrict__ b2,
                                                  const float* __restrict__ W3, const float* __restrict__ b3,
                                                  float* __restrict__ out) {
    int g = blockIdx.x;
    // lower_bound(batch, g) and lower_bound(batch, g+1), computed redundantly per thread
    int lo = 0, hi_s = NN;
    while (lo < hi_s) { int mid = (lo + hi_s) >> 1; if (batch[mid] < g) lo = mid + 1; else hi_s = mid; }
    int lo2 = lo, hi = NN;
    while (lo2 < hi) { int mid = (lo2 + hi) >> 1; if (batch[mid] < g + 1) lo2 = mid + 1; else hi = mid; }
    // nodes of graph g: [lo, hi)
    int lane = threadIdx.x & 63;
    int wave = threadIdx.x >> 6;
    float b = bL[lane];
    float s = 0.f;
    for (int n = lo + wave; n < hi; n += 4) {
        s += relu_f(dinv[n] * acc[(size_t)n * HH + lane] + b);
    }
    __shared__ float red[4][64];
    __shared__ float pv[64];
    __shared__ float tv[64];
    __shared__ float qv[32];
    red[wave][lane] = s;
    __syncthreads();
    int cnt = hi - lo;
    float invc = 1.f / (float)(cnt > 0 ? cnt : 1);
    if (threadIdx.x < 64) {
        pv[lane] = (red[0][lane] + red[1][lane] + red[2][lane] + red[3][lane]) * invc;
    }
    __syncthreads();
    if (threadIdx.x < 64) {
        int j = threadIdx.x;
        float s1 = b1[j];
        #pragma unroll
        for (int k = 0; k < 64; ++k) s1 = fmaf(pv[k], W1[k * 64 + j], s1);
        tv[j] = relu_f(s1);
    }
    __syncthreads();
    if (threadIdx.x < 32) {
        int j = threadIdx.x;
        float s2 = b2[j];
        #pragma unroll
        for (int k = 0; k < 64; ++k) s2 = fmaf(tv[k], W2[k * 32 + j], s2);
        qv[j] = relu_f(s2);
    }
    __syncthreads();
    if (threadIdx.x == 0) {
        float s3 = b3[0];
        #pragma unroll
        for (int k = 0; k < 32; ++k) s3 = fmaf(qv[k], W3[k], s3);
        out[g] = s3;
    }
}

extern "C" void kernel_launch(void* const* d_in, const int* in_sizes, int n_in,
                              void* d_out, int out_size, void* d_ws, size_t ws_size,
                              hipStream_t stream) {
    const float* x    = (const float*)d_in[0];
    const int*   ei   = (const int*)d_in[1];
    const int*   batch= (const int*)d_in[2];
    const float* Wemb = (const float*)d_in[3];
    const float* bemb = (const float*)d_in[4];
    const float* convW= (const float*)d_in[5];
    const float* convb= (const float*)d_in[6];
    const float* W1   = (const float*)d_in[7];
    const float* b1   = (const float*)d_in[8];
    const float* W2   = (const float*)d_in[9];
    const float* b2   = (const float*)d_in[10];
    const float* W3   = (const float*)d_in[11];
    const float* b3   = (const float*)d_in[12];
    float* out = (float*)d_out;

    char* ws = (char*)d_ws;
    int*   deg       = (int*)ws;                         // N
    float* dinv      = (float*)(deg + NN);               // N
    int*   row_start = (int*)(dinv + NN);                // N
    int*   cursor    = row_start + NN;                   // N
    int*   blockSums = cursor + NN;                      // 128 (pad)
    int*   csr_src   = blockSums + 128;                  // E
    float* bufA      = (float*)(csr_src + NE);           // N*64
    float* bufB      = bufA + (size_t)NN * HH;           // N*64

    const int* srcA = ei;
    const int* dstA = ei + NE;

    hipMemsetAsync(deg, 0, (size_t)NN * 4, stream);

    k_deg<<<1024, 256, 0, stream>>>(dstA, deg);
    k_dinv<<<(NN + 255) / 256, 256, 0, stream>>>(deg, dinv);
    k_scan_part<<<NB, 256, 0, stream>>>(deg, blockSums);
    k_scan_sums<<<1, 64, 0, stream>>>(blockSums);
    k_scan_final<<<NB, 256, 0, stream>>>(deg, blockSums, row_start, cursor);
    k_place<<<2048, 256, 0, stream>>>(srcA, dstA, cursor, csr_src);

    k_embed<<<(NN + 63) / 64, 256, 0, stream>>>(x, Wemb, bemb, bufA);

    int gblk = (NN + 63) / 64;
    int ablk = (NN + 3) / 4;
    // layer 0
    k_gemm64<0><<<gblk, 256, 0, stream>>>(bufA, convW + 0 * HH * HH, nullptr, dinv, bufB);
    k_agg<<<ablk, 256, 0, stream>>>(row_start, deg, csr_src, bufB, bufA);
    // layer 1
    k_gemm64<1><<<gblk, 256, 0, stream>>>(bufA, convW + 1 * HH * HH, convb + 0 * HH, dinv, bufB);
    k_agg<<<ablk, 256, 0, stream>>>(row_start, deg, csr_src, bufB, bufA);
    // layer 2
    k_gemm64<1><<<gblk, 256, 0, stream>>>(bufA, convW + 2 * HH * HH, convb + 1 * HH, dinv, bufB);
    k_agg<<<ablk, 256, 0, stream>>>(row_start, deg, csr_src, bufB, bufA);

    // fused pool + MLP (no atomics; batch sorted -> contiguous per-graph ranges)
    k_pool_mlp<<<NG, 256, 0, stream>>>(bufA, dinv, convb + 2 * HH, batch,
                                       W1, b1, W2, b2, W3, b3, out);
}

// Round 4
// 458.922 us; speedup vs baseline: 3.3285x; 1.3088x over previous
//
#include <hip/hip_runtime.h>
#include <hip/hip_bf16.h>

#define NN 100000
#define NE 1600000
#define NG 256
#define FIN 100
#define HH 64

#define BSHIFT 9
#define BSIZE 512                       // 1 << BSHIFT
#define NBUCK ((NN + BSIZE - 1) / BSIZE)  // 196
#define CHUNK 4096
#define NPLACE ((NE + CHUNK - 1) / CHUNK) // 391

__device__ __forceinline__ float relu_f(float x){ return x > 0.f ? x : 0.f; }

// ---------------- pass A: bucket counts (dst >> BSHIFT) ----------------
__global__ __launch_bounds__(256) void k_bcount(const int* __restrict__ dst,
                                                int* __restrict__ bucket_cnt) {
    __shared__ int h[NBUCK];
    int t = threadIdx.x;
    for (int i = t; i < NBUCK; i += 256) h[i] = 0;
    __syncthreads();
    int e0 = blockIdx.x * CHUNK;
    int e1 = e0 + CHUNK; if (e1 > NE) e1 = NE;
    for (int i = e0 + t; i < e1; i += 256) atomicAdd(&h[dst[i] >> BSHIFT], 1);
    __syncthreads();
    for (int i = t; i < NBUCK; i += 256) { int c = h[i]; if (c) atomicAdd(&bucket_cnt[i], c); }
}

// ---------------- scan 196 bucket counts -> starts, cursors ----------------
__global__ __launch_bounds__(256) void k_bscan(const int* __restrict__ bucket_cnt,
                                               int* __restrict__ bucket_start,
                                               int* __restrict__ bucket_cur,
                                               int* __restrict__ row_start) {
    int t = threadIdx.x;
    int lane = t & 63, wave = t >> 6;
    __shared__ int wsum[4];
    int v = (t < NBUCK) ? bucket_cnt[t] : 0;
    int inc = v;
    for (int off = 1; off < 64; off <<= 1) {
        int n = __shfl_up(inc, off, 64);
        if (lane >= off) inc += n;
    }
    if (lane == 63) wsum[wave] = inc;
    __syncthreads();
    int woff = 0;
    for (int w = 0; w < wave; ++w) woff += wsum[w];
    int excl = woff + inc - v;
    if (t < NBUCK) { bucket_start[t] = excl; bucket_cur[t] = excl; }
    if (t == 0) { bucket_start[NBUCK] = NE; row_start[NN] = NE; }
}

// ---------------- pass B: place (src,dst) pairs into bucket regions ----------------
__global__ __launch_bounds__(256) void k_bplace(const int* __restrict__ src,
                                                const int* __restrict__ dst,
                                                int* __restrict__ bucket_cur,
                                                int2* __restrict__ pairs) {
    __shared__ int h[NBUCK];
    __shared__ int base[NBUCK];
    int t = threadIdx.x;
    for (int i = t; i < NBUCK; i += 256) h[i] = 0;
    __syncthreads();
    int e0 = blockIdx.x * CHUNK;
    int e1 = e0 + CHUNK; if (e1 > NE) e1 = NE;
    for (int i = e0 + t; i < e1; i += 256) atomicAdd(&h[dst[i] >> BSHIFT], 1);
    __syncthreads();
    for (int i = t; i < NBUCK; i += 256) {
        int c = h[i];
        base[i] = c ? atomicAdd(&bucket_cur[i], c) : 0;
    }
    __syncthreads();
    for (int i = t; i < NBUCK; i += 256) h[i] = 0;   // reuse as local cursor
    __syncthreads();
    for (int i = e0 + t; i < e1; i += 256) {
        int d = dst[i];
        int b = d >> BSHIFT;
        int pos = base[b] + atomicAdd(&h[b], 1);
        pairs[pos] = make_int2(src[i], d);
    }
}

// ---------------- per-bucket CSR finalize: row_start, dinv, csr_src ----------------
__global__ __launch_bounds__(256) void k_csr(const int* __restrict__ bucket_start,
                                             const int2* __restrict__ pairs,
                                             int* __restrict__ row_start,
                                             float* __restrict__ dinv,
                                             int* __restrict__ csr_src) {
    int b = blockIdx.x;
    int nbase = b << BSHIFT;
    int ncnt = NN - nbase; if (ncnt > BSIZE) ncnt = BSIZE;
    __shared__ int degl[BSIZE];
    __shared__ int curl[BSIZE];
    __shared__ int wsum[8];
    int t = threadIdx.x;
    int lane = t & 63, wave = t >> 6;
    for (int i = t; i < BSIZE; i += 256) degl[i] = 0;
    __syncthreads();
    int p0 = bucket_start[b], p1 = bucket_start[b + 1];
    for (int i = p0 + t; i < p1; i += 256) atomicAdd(&degl[pairs[i].y - nbase], 1);
    __syncthreads();
    // scan 512 degrees: 8 segments of 64 across 4 waves (2 segs/wave)
    int vals[2], incs[2];
    #pragma unroll
    for (int k = 0; k < 2; ++k) {
        int seg = wave + k * 4;
        int v = degl[seg * 64 + lane];
        int inc = v;
        for (int off = 1; off < 64; off <<= 1) {
            int n = __shfl_up(inc, off, 64);
            if (lane >= off) inc += n;
        }
        vals[k] = v; incs[k] = inc;
        if (lane == 63) wsum[seg] = inc;
    }
    __syncthreads();
    #pragma unroll
    for (int k = 0; k < 2; ++k) {
        int seg = wave + k * 4;
        int soff = 0;
        for (int s = 0; s < 8; ++s) if (s < seg) soff += wsum[s];
        int idx = seg * 64 + lane;
        int rs = p0 + soff + incs[k] - vals[k];   // exclusive prefix, global position
        curl[idx] = rs;
        if (idx < ncnt) {
            row_start[nbase + idx] = rs;
            dinv[nbase + idx] = rsqrtf((float)(vals[k] + 1));
        }
    }
    __syncthreads();
    for (int i = p0 + t; i < p1; i += 256) {
        int2 p = pairs[i];
        int pos = atomicAdd(&curl[p.y - nbase], 1);
        csr_src[pos] = p.x;
    }
}

// ---------------- embed: h = relu(x @ W_emb + b) ----------------
__global__ __launch_bounds__(256) void k_embed(const float* __restrict__ x,
                                               const float* __restrict__ Wemb,
                                               const float* __restrict__ bemb,
                                               float* __restrict__ h) {
    __shared__ __align__(16) float Wl[FIN * HH];
    __shared__ __align__(16) float Xl[64 * FIN];
    int tid = threadIdx.x;
    for (int i = tid; i < FIN * HH; i += 256) Wl[i] = Wemb[i];
    int row0 = blockIdx.x * 64;
    const float* xs = x + (size_t)row0 * FIN;
    int lim = (NN - row0 < 64 ? NN - row0 : 64) * FIN;
    for (int i = tid; i < 64 * FIN; i += 256) Xl[i] = (i < lim) ? xs[i] : 0.f;
    __syncthreads();

    int wave = tid >> 6, lane = tid & 63;
    int rbase = wave * 16;
    float acc[16];
    #pragma unroll
    for (int r = 0; r < 16; ++r) acc[r] = 0.f;

    for (int k = 0; k < FIN; k += 4) {
        float w0 = Wl[(k+0)*HH + lane];
        float w1 = Wl[(k+1)*HH + lane];
        float w2 = Wl[(k+2)*HH + lane];
        float w3 = Wl[(k+3)*HH + lane];
        #pragma unroll
        for (int r = 0; r < 16; ++r) {
            const float4 xv = *reinterpret_cast<const float4*>(&Xl[(rbase + r) * FIN + k]);
            acc[r] = fmaf(xv.x, w0, acc[r]);
            acc[r] = fmaf(xv.y, w1, acc[r]);
            acc[r] = fmaf(xv.z, w2, acc[r]);
            acc[r] = fmaf(xv.w, w3, acc[r]);
        }
    }
    float b = bemb[lane];
    #pragma unroll
    for (int r = 0; r < 16; ++r) {
        int row = row0 + rbase + r;
        if (row < NN) h[(size_t)row * HH + lane] = relu_f(acc[r] + b);
    }
}

// ---------------- per-layer GEMM: g = dinv * (T(X) @ W) ----------------
// MODE 0: T(x) = x; MODE 1: T(x) = relu(dinv[row]*x + bprev[k])
template <int MODE>
__global__ __launch_bounds__(256) void k_gemm64(const float* __restrict__ X,
                                                const float* __restrict__ W,
                                                const float* __restrict__ bprev,
                                                const float* __restrict__ dinv,
                                                float* __restrict__ g) {
    __shared__ __align__(16) float Wl[HH * HH];
    __shared__ __align__(16) float Xl[64 * HH];
    int tid = threadIdx.x;
    for (int i = tid; i < HH * HH; i += 256) Wl[i] = W[i];
    int row0 = blockIdx.x * 64;
    for (int i = tid; i < 64 * HH; i += 256) {
        int r = i >> 6, k = i & 63;
        int row = row0 + r;
        float v = 0.f;
        if (row < NN) {
            v = X[(size_t)row * HH + k];
            if (MODE == 1) v = relu_f(dinv[row] * v + bprev[k]);
        }
        Xl[i] = v;
    }
    __syncthreads();

    int wave = tid >> 6, lane = tid & 63;
    int rbase = wave * 16;
    float acc[16];
    #pragma unroll
    for (int r = 0; r < 16; ++r) acc[r] = 0.f;

    for (int k = 0; k < HH; k += 4) {
        float w0 = Wl[(k+0)*HH + lane];
        float w1 = Wl[(k+1)*HH + lane];
        float w2 = Wl[(k+2)*HH + lane];
        float w3 = Wl[(k+3)*HH + lane];
        #pragma unroll
        for (int r = 0; r < 16; ++r) {
            const float4 xv = *reinterpret_cast<const float4*>(&Xl[(rbase + r) * HH + k]);
            acc[r] = fmaf(xv.x, w0, acc[r]);
            acc[r] = fmaf(xv.y, w1, acc[r]);
            acc[r] = fmaf(xv.z, w2, acc[r]);
            acc[r] = fmaf(xv.w, w3, acc[r]);
        }
    }
    #pragma unroll
    for (int r = 0; r < 16; ++r) {
        int row = row0 + rbase + r;
        if (row < NN) g[(size_t)row * HH + lane] = dinv[row] * acc[r];
    }
}

// ---------------- CSR aggregate: out[v] = g[v] + sum_{e in in(v)} g[src[e]] ----------------
__global__ __launch_bounds__(256) void k_agg(const int* __restrict__ row_start,
                                             const int* __restrict__ csr_src,
                                             const float* __restrict__ g,
                                             float* __restrict__ out) {
    int lane = threadIdx.x & 63;
    int wave = threadIdx.x >> 6;
    int v = blockIdx.x * 4 + wave;
    if (v >= NN) return;
    int start = row_start[v];
    int n = row_start[v + 1] - start;
    float acc = g[(size_t)v * HH + lane];          // self loop
    for (int base = 0; base < n; base += 64) {
        int m = n - base; if (m > 64) m = 64;
        int sv = (lane < m) ? csr_src[start + base + lane] : 0;
        int j = 0;
        for (; j + 4 <= m; j += 4) {
            int s0 = __shfl(sv, j), s1 = __shfl(sv, j + 1);
            int s2 = __shfl(sv, j + 2), s3 = __shfl(sv, j + 3);
            float a0 = g[(size_t)s0 * HH + lane];
            float a1 = g[(size_t)s1 * HH + lane];
            float a2 = g[(size_t)s2 * HH + lane];
            float a3 = g[(size_t)s3 * HH + lane];
            acc += a0; acc += a1; acc += a2; acc += a3;
        }
        for (; j < m; ++j) {
            int s = __shfl(sv, j);
            acc += g[(size_t)s * HH + lane];
        }
    }
    out[(size_t)v * HH + lane] = acc;
}

// ---------------- fused pool + MLP: one block per graph, zero atomics ----------------
__global__ __launch_bounds__(256) void k_pool_mlp(const float* __restrict__ acc,
                                                  const float* __restrict__ dinv,
                                                  const float* __restrict__ bL,
                                                  const int* __restrict__ batch,
                                                  const float* __restrict__ W1, const float* __restrict__ b1,
                                                  const float* __restrict__ W2, const float* __restrict__ b2,
                                                  const float* __restrict__ W3, const float* __restrict__ b3,
                                                  float* __restrict__ out) {
    int g = blockIdx.x;
    int lo = 0, hi_s = NN;
    while (lo < hi_s) { int mid = (lo + hi_s) >> 1; if (batch[mid] < g) lo = mid + 1; else hi_s = mid; }
    int lo2 = lo, hi = NN;
    while (lo2 < hi) { int mid = (lo2 + hi) >> 1; if (batch[mid] < g + 1) lo2 = mid + 1; else hi = mid; }
    int lane = threadIdx.x & 63;
    int wave = threadIdx.x >> 6;
    float b = bL[lane];
    float s = 0.f;
    for (int n = lo + wave; n < hi; n += 4) {
        s += relu_f(dinv[n] * acc[(size_t)n * HH + lane] + b);
    }
    __shared__ float red[4][64];
    __shared__ float pv[64];
    __shared__ float tv[64];
    __shared__ float qv[32];
    red[wave][lane] = s;
    __syncthreads();
    int cnt = hi - lo;
    float invc = 1.f / (float)(cnt > 0 ? cnt : 1);
    if (threadIdx.x < 64) {
        pv[lane] = (red[0][lane] + red[1][lane] + red[2][lane] + red[3][lane]) * invc;
    }
    __syncthreads();
    if (threadIdx.x < 64) {
        int j = threadIdx.x;
        float s1 = b1[j];
        #pragma unroll
        for (int k = 0; k < 64; ++k) s1 = fmaf(pv[k], W1[k * 64 + j], s1);
        tv[j] = relu_f(s1);
    }
    __syncthreads();
    if (threadIdx.x < 32) {
        int j = threadIdx.x;
        float s2 = b2[j];
        #pragma unroll
        for (int k = 0; k < 64; ++k) s2 = fmaf(tv[k], W2[k * 32 + j], s2);
        qv[j] = relu_f(s2);
    }
    __syncthreads();
    if (threadIdx.x == 0) {
        float s3 = b3[0];
        #pragma unroll
        for (int k = 0; k < 32; ++k) s3 = fmaf(qv[k], W3[k], s3);
        out[g] = s3;
    }
}

extern "C" void kernel_launch(void* const* d_in, const int* in_sizes, int n_in,
                              void* d_out, int out_size, void* d_ws, size_t ws_size,
                              hipStream_t stream) {
    const float* x    = (const float*)d_in[0];
    const int*   ei   = (const int*)d_in[1];
    const int*   batch= (const int*)d_in[2];
    const float* Wemb = (const float*)d_in[3];
    const float* bemb = (const float*)d_in[4];
    const float* convW= (const float*)d_in[5];
    const float* convb= (const float*)d_in[6];
    const float* W1   = (const float*)d_in[7];
    const float* b1   = (const float*)d_in[8];
    const float* W2   = (const float*)d_in[9];
    const float* b2   = (const float*)d_in[10];
    const float* W3   = (const float*)d_in[11];
    const float* b3   = (const float*)d_in[12];
    float* out = (float*)d_out;

    // workspace layout (256B-aligned regions)
    auto alignup = [](size_t x) { return (x + 255) & ~(size_t)255; };
    char* p = (char*)d_ws;
    int*   row_start    = (int*)p;            p += alignup((size_t)(NN + 1) * 4);
    float* dinv         = (float*)p;          p += alignup((size_t)NN * 4);
    int*   bucket_cnt   = (int*)p;            p += alignup((size_t)NBUCK * 4);
    int*   bucket_start = (int*)p;            p += alignup((size_t)(NBUCK + 1) * 4);
    int*   bucket_cur   = (int*)p;            p += alignup((size_t)NBUCK * 4);
    int*   csr_src      = (int*)p;            p += alignup((size_t)NE * 4);
    float* bufA         = (float*)p;          p += alignup((size_t)NN * HH * 4);
    float* bufB         = (float*)p;
    int2*  pairs        = (int2*)bufA;        // aliased: pairs dead before k_embed writes bufA

    const int* srcA = ei;
    const int* dstA = ei + NE;

    hipMemsetAsync(bucket_cnt, 0, (size_t)NBUCK * 4, stream);

    k_bcount<<<NPLACE, 256, 0, stream>>>(dstA, bucket_cnt);
    k_bscan<<<1, 256, 0, stream>>>(bucket_cnt, bucket_start, bucket_cur, row_start);
    k_bplace<<<NPLACE, 256, 0, stream>>>(srcA, dstA, bucket_cur, pairs);
    k_csr<<<NBUCK, 256, 0, stream>>>(bucket_start, pairs, row_start, dinv, csr_src);

    k_embed<<<(NN + 63) / 64, 256, 0, stream>>>(x, Wemb, bemb, bufA);

    int gblk = (NN + 63) / 64;
    int ablk = (NN + 3) / 4;
    // layer 0
    k_gemm64<0><<<gblk, 256, 0, stream>>>(bufA, convW + 0 * HH * HH, nullptr, dinv, bufB);
    k_agg<<<ablk, 256, 0, stream>>>(row_start, csr_src, bufB, bufA);
    // layer 1
    k_gemm64<1><<<gblk, 256, 0, stream>>>(bufA, convW + 1 * HH * HH, convb + 0 * HH, dinv, bufB);
    k_agg<<<ablk, 256, 0, stream>>>(row_start, csr_src, bufB, bufA);
    // layer 2
    k_gemm64<1><<<gblk, 256, 0, stream>>>(bufA, convW + 2 * HH * HH, convb + 1 * HH, dinv, bufB);
    k_agg<<<ablk, 256, 0, stream>>>(row_start, csr_src, bufB, bufA);

    // fused pool + MLP
    k_pool_mlp<<<NG, 256, 0, stream>>>(bufA, dinv, convb + 2 * HH, batch,
                                       W1, b1, W2, b2, W3, b3, out);
}

// Round 5
// 320.401 us; speedup vs baseline: 4.7676x; 1.4323x over previous
//
#include <hip/hip_runtime.h>
#include <hip/hip_bf16.h>

#define NN 100000
#define NE 1600000
#define NG 256
#define FIN 100
#define HH 64

#define BSHIFT 9
#define BSIZE 512
#define NBUCK ((NN + BSIZE - 1) / BSIZE)  // 196
#define CHUNK 4096
#define NPLACE ((NE + CHUNK - 1) / CHUNK) // 391

typedef __attribute__((ext_vector_type(8))) short short8;
typedef __attribute__((ext_vector_type(4))) float f32x4;

__device__ __forceinline__ float relu_f(float x){ return x > 0.f ? x : 0.f; }
__device__ __forceinline__ unsigned short f2b(float f) {
    unsigned int u = __float_as_uint(f);
    u += 0x7fffu + ((u >> 16) & 1u);      // round-to-nearest-even
    return (unsigned short)(u >> 16);
}
__device__ __forceinline__ float b2f(unsigned short h) {
    return __uint_as_float(((unsigned int)h) << 16);
}

// ================= CSR build (unchanged from R4) =================
__global__ __launch_bounds__(256) void k_bcount(const int* __restrict__ dst,
                                                int* __restrict__ bucket_cnt) {
    __shared__ int h[NBUCK];
    int t = threadIdx.x;
    for (int i = t; i < NBUCK; i += 256) h[i] = 0;
    __syncthreads();
    int e0 = blockIdx.x * CHUNK;
    int e1 = e0 + CHUNK; if (e1 > NE) e1 = NE;
    for (int i = e0 + t; i < e1; i += 256) atomicAdd(&h[dst[i] >> BSHIFT], 1);
    __syncthreads();
    for (int i = t; i < NBUCK; i += 256) { int c = h[i]; if (c) atomicAdd(&bucket_cnt[i], c); }
}

__global__ __launch_bounds__(256) void k_bscan(const int* __restrict__ bucket_cnt,
                                               int* __restrict__ bucket_start,
                                               int* __restrict__ bucket_cur,
                                               int* __restrict__ row_start) {
    int t = threadIdx.x;
    int lane = t & 63, wave = t >> 6;
    __shared__ int wsum[4];
    int v = (t < NBUCK) ? bucket_cnt[t] : 0;
    int inc = v;
    for (int off = 1; off < 64; off <<= 1) {
        int n = __shfl_up(inc, off, 64);
        if (lane >= off) inc += n;
    }
    if (lane == 63) wsum[wave] = inc;
    __syncthreads();
    int woff = 0;
    for (int w = 0; w < wave; ++w) woff += wsum[w];
    int excl = woff + inc - v;
    if (t < NBUCK) { bucket_start[t] = excl; bucket_cur[t] = excl; }
    if (t == 0) { bucket_start[NBUCK] = NE; row_start[NN] = NE; }
}

__global__ __launch_bounds__(256) void k_bplace(const int* __restrict__ src,
                                                const int* __restrict__ dst,
                                                int* __restrict__ bucket_cur,
                                                int2* __restrict__ pairs) {
    __shared__ int h[NBUCK];
    __shared__ int base[NBUCK];
    int t = threadIdx.x;
    for (int i = t; i < NBUCK; i += 256) h[i] = 0;
    __syncthreads();
    int e0 = blockIdx.x * CHUNK;
    int e1 = e0 + CHUNK; if (e1 > NE) e1 = NE;
    for (int i = e0 + t; i < e1; i += 256) atomicAdd(&h[dst[i] >> BSHIFT], 1);
    __syncthreads();
    for (int i = t; i < NBUCK; i += 256) {
        int c = h[i];
        base[i] = c ? atomicAdd(&bucket_cur[i], c) : 0;
    }
    __syncthreads();
    for (int i = t; i < NBUCK; i += 256) h[i] = 0;
    __syncthreads();
    for (int i = e0 + t; i < e1; i += 256) {
        int d = dst[i];
        int b = d >> BSHIFT;
        int pos = base[b] + atomicAdd(&h[b], 1);
        pairs[pos] = make_int2(src[i], d);
    }
}

__global__ __launch_bounds__(256) void k_csr(const int* __restrict__ bucket_start,
                                             const int2* __restrict__ pairs,
                                             int* __restrict__ row_start,
                                             float* __restrict__ dinv,
                                             int* __restrict__ csr_src) {
    int b = blockIdx.x;
    int nbase = b << BSHIFT;
    int ncnt = NN - nbase; if (ncnt > BSIZE) ncnt = BSIZE;
    __shared__ int degl[BSIZE];
    __shared__ int curl[BSIZE];
    __shared__ int wsum[8];
    int t = threadIdx.x;
    int lane = t & 63, wave = t >> 6;
    for (int i = t; i < BSIZE; i += 256) degl[i] = 0;
    __syncthreads();
    int p0 = bucket_start[b], p1 = bucket_start[b + 1];
    for (int i = p0 + t; i < p1; i += 256) atomicAdd(&degl[pairs[i].y - nbase], 1);
    __syncthreads();
    int vals[2], incs[2];
    #pragma unroll
    for (int k = 0; k < 2; ++k) {
        int seg = wave + k * 4;
        int v = degl[seg * 64 + lane];
        int inc = v;
        for (int off = 1; off < 64; off <<= 1) {
            int n = __shfl_up(inc, off, 64);
            if (lane >= off) inc += n;
        }
        vals[k] = v; incs[k] = inc;
        if (lane == 63) wsum[seg] = inc;
    }
    __syncthreads();
    #pragma unroll
    for (int k = 0; k < 2; ++k) {
        int seg = wave + k * 4;
        int soff = 0;
        for (int s = 0; s < 8; ++s) if (s < seg) soff += wsum[s];
        int idx = seg * 64 + lane;
        int rs = p0 + soff + incs[k] - vals[k];
        curl[idx] = rs;
        if (idx < ncnt) {
            row_start[nbase + idx] = rs;
            dinv[nbase + idx] = rsqrtf((float)(vals[k] + 1));
        }
    }
    __syncthreads();
    for (int i = p0 + t; i < p1; i += 256) {
        int2 p = pairs[i];
        int pos = atomicAdd(&curl[p.y - nbase], 1);
        csr_src[pos] = p.x;
    }
}

// ================= embed: h = relu(x @ W_emb + b), bf16 MFMA =================
// K = 100 padded to 128. LDS rows padded +8 bf16 (stride 136) -> 2-way-conflict-free b128.
#define SXE 136
__global__ __launch_bounds__(256) void k_embed_mfma(const float* __restrict__ x,
                                                    const float* __restrict__ Wemb,
                                                    const float* __restrict__ bemb,
                                                    unsigned short* __restrict__ h) {
    __shared__ unsigned short Xl[64 * SXE];   // 17.4 KB
    __shared__ unsigned short Wt[64 * SXE];   // 17.4 KB (transposed W)
    __shared__ float bl[64];
    int t = threadIdx.x;
    // zero (covers K padding 100..127)
    for (int i = t; i < 64 * SXE; i += 256) { Xl[i] = 0; Wt[i] = 0; }
    if (t < 64) bl[t] = bemb[t];
    __syncthreads();
    int row0 = blockIdx.x * 64;
    // stage X rows (fp32 -> bf16)
    for (int i = t; i < 64 * FIN; i += 256) {
        int r = i / FIN, c = i - r * FIN;
        int row = row0 + r;
        if (row < NN) Xl[r * SXE + c] = f2b(x[(size_t)row * FIN + c]);
    }
    // stage W transposed: Wt[n][k] = W[k][n]
    for (int i = t; i < FIN * HH; i += 256) {
        int k = i >> 6, n = i & 63;
        Wt[n * SXE + k] = f2b(Wemb[i]);
    }
    __syncthreads();

    int w = t >> 6, l = t & 63;
    int m16 = l & 15, g4 = l >> 4;
    f32x4 acc[4] = {{0,0,0,0},{0,0,0,0},{0,0,0,0},{0,0,0,0}};
    const unsigned short* Arow = &Xl[(w * 16 + m16) * SXE + g4 * 8];
    #pragma unroll
    for (int kk = 0; kk < 4; ++kk) {          // K = 128
        short8 a = *reinterpret_cast<const short8*>(Arow + kk * 32);
        #pragma unroll
        for (int c = 0; c < 4; ++c) {
            short8 bfr = *reinterpret_cast<const short8*>(&Wt[(c * 16 + m16) * SXE + g4 * 8 + kk * 32]);
            acc[c] = __builtin_amdgcn_mfma_f32_16x16x32_bf16(a, bfr, acc[c], 0, 0, 0);
        }
    }
    #pragma unroll
    for (int c = 0; c < 4; ++c) {
        int col = c * 16 + m16;
        float bb = bl[col];
        #pragma unroll
        for (int r = 0; r < 4; ++r) {
            int row = row0 + w * 16 + g4 * 4 + r;
            if (row < NN) h[(size_t)row * HH + col] = f2b(relu_f(acc[c][r] + bb));
        }
    }
}

// ================= conv GEMM: g = dinv * (h @ W), bf16 MFMA =================
#define SXC 72
__global__ __launch_bounds__(256) void k_gemm_mfma(const unsigned short* __restrict__ X,
                                                   const float* __restrict__ W,
                                                   const float* __restrict__ dinv,
                                                   unsigned short* __restrict__ g) {
    __shared__ unsigned short Xl[64 * SXC];   // 9.2 KB
    __shared__ unsigned short Wt[64 * SXC];   // 9.2 KB
    int t = threadIdx.x;
    int row0 = blockIdx.x * 64;
    // stage X (bf16, short8 vector loads)
    for (int i = t; i < 64 * HH / 8; i += 256) {
        int r = i >> 3, c8 = i & 7;
        int row = row0 + r;
        short8 v = {0,0,0,0,0,0,0,0};
        if (row < NN) v = *reinterpret_cast<const short8*>(&X[(size_t)row * HH + c8 * 8]);
        *reinterpret_cast<short8*>(&Xl[r * SXC + c8 * 8]) = v;
    }
    // stage W transposed (fp32 -> bf16)
    for (int i = t; i < HH * HH; i += 256) {
        int k = i >> 6, n = i & 63;
        Wt[n * SXC + k] = f2b(W[i]);
    }
    __syncthreads();

    int w = t >> 6, l = t & 63;
    int m16 = l & 15, g4 = l >> 4;
    f32x4 acc[4] = {{0,0,0,0},{0,0,0,0},{0,0,0,0},{0,0,0,0}};
    const unsigned short* Arow = &Xl[(w * 16 + m16) * SXC + g4 * 8];
    #pragma unroll
    for (int kk = 0; kk < 2; ++kk) {          // K = 64
        short8 a = *reinterpret_cast<const short8*>(Arow + kk * 32);
        #pragma unroll
        for (int c = 0; c < 4; ++c) {
            short8 bfr = *reinterpret_cast<const short8*>(&Wt[(c * 16 + m16) * SXC + g4 * 8 + kk * 32]);
            acc[c] = __builtin_amdgcn_mfma_f32_16x16x32_bf16(a, bfr, acc[c], 0, 0, 0);
        }
    }
    float dv[4];
    #pragma unroll
    for (int r = 0; r < 4; ++r) {
        int row = row0 + w * 16 + g4 * 4 + r;
        dv[r] = (row < NN) ? dinv[row] : 0.f;
    }
    #pragma unroll
    for (int c = 0; c < 4; ++c) {
        int col = c * 16 + m16;
        #pragma unroll
        for (int r = 0; r < 4; ++r) {
            int row = row0 + w * 16 + g4 * 4 + r;
            if (row < NN) g[(size_t)row * HH + col] = f2b(dv[r] * acc[c][r]);
        }
    }
}

// ====== CSR aggregate + layer finalize: h[v] = relu(dinv*(g[v]+sum g[src]) + b) ======
__global__ __launch_bounds__(256) void k_agg_bf(const int* __restrict__ row_start,
                                                const int* __restrict__ csr_src,
                                                const unsigned short* __restrict__ g,
                                                const float* __restrict__ dinv,
                                                const float* __restrict__ bL,
                                                unsigned short* __restrict__ h) {
    int lane = threadIdx.x & 63;
    int wave = threadIdx.x >> 6;
    int v = blockIdx.x * 4 + wave;
    if (v >= NN) return;
    float b = bL[lane];
    int start = row_start[v];
    int n = row_start[v + 1] - start;
    float acc = b2f(g[(size_t)v * HH + lane]);       // self loop
    for (int base = 0; base < n; base += 64) {
        int m = n - base; if (m > 64) m = 64;
        int sv = (lane < m) ? csr_src[start + base + lane] : 0;
        int j = 0;
        for (; j + 4 <= m; j += 4) {
            int s0 = __shfl(sv, j), s1 = __shfl(sv, j + 1);
            int s2 = __shfl(sv, j + 2), s3 = __shfl(sv, j + 3);
            float a0 = b2f(g[(size_t)s0 * HH + lane]);
            float a1 = b2f(g[(size_t)s1 * HH + lane]);
            float a2 = b2f(g[(size_t)s2 * HH + lane]);
            float a3 = b2f(g[(size_t)s3 * HH + lane]);
            acc += a0; acc += a1; acc += a2; acc += a3;
        }
        for (; j < m; ++j) {
            int s = __shfl(sv, j);
            acc += b2f(g[(size_t)s * HH + lane]);
        }
    }
    h[(size_t)v * HH + lane] = f2b(relu_f(dinv[v] * acc + b));
}

// ================= fused pool + MLP (h already activated) =================
__global__ __launch_bounds__(256) void k_pool_mlp(const unsigned short* __restrict__ h,
                                                  const int* __restrict__ batch,
                                                  const float* __restrict__ W1, const float* __restrict__ b1,
                                                  const float* __restrict__ W2, const float* __restrict__ b2,
                                                  const float* __restrict__ W3, const float* __restrict__ b3,
                                                  float* __restrict__ out) {
    int g = blockIdx.x;
    int lo = 0, hi_s = NN;
    while (lo < hi_s) { int mid = (lo + hi_s) >> 1; if (batch[mid] < g) lo = mid + 1; else hi_s = mid; }
    int lo2 = lo, hi = NN;
    while (lo2 < hi) { int mid = (lo2 + hi) >> 1; if (batch[mid] < g + 1) lo2 = mid + 1; else hi = mid; }
    int lane = threadIdx.x & 63;
    int wave = threadIdx.x >> 6;
    float s = 0.f;
    for (int n = lo + wave; n < hi; n += 4) {
        s += b2f(h[(size_t)n * HH + lane]);
    }
    __shared__ float red[4][64];
    __shared__ float pv[64];
    __shared__ float tv[64];
    __shared__ float qv[32];
    red[wave][lane] = s;
    __syncthreads();
    int cnt = hi - lo;
    float invc = 1.f / (float)(cnt > 0 ? cnt : 1);
    if (threadIdx.x < 64) {
        pv[lane] = (red[0][lane] + red[1][lane] + red[2][lane] + red[3][lane]) * invc;
    }
    __syncthreads();
    if (threadIdx.x < 64) {
        int j = threadIdx.x;
        float s1 = b1[j];
        #pragma unroll
        for (int k = 0; k < 64; ++k) s1 = fmaf(pv[k], W1[k * 64 + j], s1);
        tv[j] = relu_f(s1);
    }
    __syncthreads();
    if (threadIdx.x < 32) {
        int j = threadIdx.x;
        float s2 = b2[j];
        #pragma unroll
        for (int k = 0; k < 64; ++k) s2 = fmaf(tv[k], W2[k * 32 + j], s2);
        qv[j] = relu_f(s2);
    }
    __syncthreads();
    if (threadIdx.x == 0) {
        float s3 = b3[0];
        #pragma unroll
        for (int k = 0; k < 32; ++k) s3 = fmaf(qv[k], W3[k], s3);
        out[g] = s3;
    }
}

extern "C" void kernel_launch(void* const* d_in, const int* in_sizes, int n_in,
                              void* d_out, int out_size, void* d_ws, size_t ws_size,
                              hipStream_t stream) {
    const float* x    = (const float*)d_in[0];
    const int*   ei   = (const int*)d_in[1];
    const int*   batch= (const int*)d_in[2];
    const float* Wemb = (const float*)d_in[3];
    const float* bemb = (const float*)d_in[4];
    const float* convW= (const float*)d_in[5];
    const float* convb= (const float*)d_in[6];
    const float* W1   = (const float*)d_in[7];
    const float* b1   = (const float*)d_in[8];
    const float* W2   = (const float*)d_in[9];
    const float* b2   = (const float*)d_in[10];
    const float* W3   = (const float*)d_in[11];
    const float* b3   = (const float*)d_in[12];
    float* out = (float*)d_out;

    auto alignup = [](size_t v) { return (v + 255) & ~(size_t)255; };
    char* p = (char*)d_ws;
    int*   row_start    = (int*)p;            p += alignup((size_t)(NN + 1) * 4);
    float* dinv         = (float*)p;          p += alignup((size_t)NN * 4);
    int*   bucket_cnt   = (int*)p;            p += alignup((size_t)NBUCK * 4);
    int*   bucket_start = (int*)p;            p += alignup((size_t)(NBUCK + 1) * 4);
    int*   bucket_cur   = (int*)p;            p += alignup((size_t)NBUCK * 4);
    int*   csr_src      = (int*)p;            p += alignup((size_t)NE * 4);
    unsigned short* hbuf = (unsigned short*)p; p += alignup((size_t)NN * HH * 2);
    unsigned short* gbuf = (unsigned short*)p; p += alignup((size_t)NN * HH * 2);
    int2*  pairs        = (int2*)hbuf;        // aliased: pairs dead before k_embed writes hbuf
    // NOTE: pairs needs NE*8 = 12.8 MB = NN*HH*2 exactly; hbuf is 12.8 MB. OK.

    const int* srcA = ei;
    const int* dstA = ei + NE;

    hipMemsetAsync(bucket_cnt, 0, (size_t)NBUCK * 4, stream);

    k_bcount<<<NPLACE, 256, 0, stream>>>(dstA, bucket_cnt);
    k_bscan<<<1, 256, 0, stream>>>(bucket_cnt, bucket_start, bucket_cur, row_start);
    k_bplace<<<NPLACE, 256, 0, stream>>>(srcA, dstA, bucket_cur, pairs);
    k_csr<<<NBUCK, 256, 0, stream>>>(bucket_start, pairs, row_start, dinv, csr_src);

    int gblk = (NN + 63) / 64;
    int ablk = (NN + 3) / 4;

    k_embed_mfma<<<gblk, 256, 0, stream>>>(x, Wemb, bemb, hbuf);

    // layer 0
    k_gemm_mfma<<<gblk, 256, 0, stream>>>(hbuf, convW + 0 * HH * HH, dinv, gbuf);
    k_agg_bf<<<ablk, 256, 0, stream>>>(row_start, csr_src, gbuf, dinv, convb + 0 * HH, hbuf);
    // layer 1
    k_gemm_mfma<<<gblk, 256, 0, stream>>>(hbuf, convW + 1 * HH * HH, dinv, gbuf);
    k_agg_bf<<<ablk, 256, 0, stream>>>(row_start, csr_src, gbuf, dinv, convb + 1 * HH, hbuf);
    // layer 2
    k_gemm_mfma<<<gblk, 256, 0, stream>>>(hbuf, convW + 2 * HH * HH, dinv, gbuf);
    k_agg_bf<<<ablk, 256, 0, stream>>>(row_start, csr_src, gbuf, dinv, convb + 2 * HH, hbuf);

    k_pool_mlp<<<NG, 256, 0, stream>>>(hbuf, batch, W1, b1, W2, b2, W3, b3, out);
}

// Round 6
// 307.322 us; speedup vs baseline: 4.9705x; 1.0426x over previous
//
#include <hip/hip_runtime.h>
#include <hip/hip_bf16.h>

#define NN 100000
#define NE 1600000
#define NG 256
#define FIN 100
#define HH 64

#define BSHIFT 9
#define BSIZE 512
#define NBUCK ((NN + BSIZE - 1) / BSIZE)   // 196
#define CHUNK 4096
#define NPLACE ((NE + CHUNK - 1) / CHUNK)  // 391

#define NBLK64 ((NN + 63) / 64)            // 1563
#define NWAVE (NBLK64 * 4)                 // 6252
#define MAXSEG 4

typedef __attribute__((ext_vector_type(8))) short short8;
typedef __attribute__((ext_vector_type(4))) float f32x4;

__device__ __forceinline__ float relu_f(float x){ return x > 0.f ? x : 0.f; }
__device__ __forceinline__ unsigned short f2b(float f) {
    unsigned int u = __float_as_uint(f);
    u += 0x7fffu + ((u >> 16) & 1u);
    return (unsigned short)(u >> 16);
}
__device__ __forceinline__ float b2f(unsigned short h) {
    return __uint_as_float(((unsigned int)h) << 16);
}

// ================= CSR build =================
__global__ __launch_bounds__(256) void k_bcount(const int* __restrict__ dst,
                                                int* __restrict__ bucket_cnt) {
    __shared__ int h[NBUCK];
    int t = threadIdx.x;
    for (int i = t; i < NBUCK; i += 256) h[i] = 0;
    __syncthreads();
    int e0 = blockIdx.x * CHUNK;
    int e1 = e0 + CHUNK; if (e1 > NE) e1 = NE;
    for (int i = e0 + t; i < e1; i += 256) atomicAdd(&h[dst[i] >> BSHIFT], 1);
    __syncthreads();
    for (int i = t; i < NBUCK; i += 256) { int c = h[i]; if (c) atomicAdd(&bucket_cnt[i], c); }
}

__global__ __launch_bounds__(256) void k_bscan(const int* __restrict__ bucket_cnt,
                                               int* __restrict__ bucket_start,
                                               int* __restrict__ bucket_cur,
                                               int* __restrict__ row_start) {
    int t = threadIdx.x;
    int lane = t & 63, wave = t >> 6;
    __shared__ int wsum[4];
    int v = (t < NBUCK) ? bucket_cnt[t] : 0;
    int inc = v;
    for (int off = 1; off < 64; off <<= 1) {
        int n = __shfl_up(inc, off, 64);
        if (lane >= off) inc += n;
    }
    if (lane == 63) wsum[wave] = inc;
    __syncthreads();
    int woff = 0;
    for (int w = 0; w < wave; ++w) woff += wsum[w];
    int excl = woff + inc - v;
    if (t < NBUCK) { bucket_start[t] = excl; bucket_cur[t] = excl; }
    if (t == 0) { bucket_start[NBUCK] = NE; row_start[NN] = NE; }
}

// pack: (local_dst 9b << 17) | src 17b
__global__ __launch_bounds__(256) void k_bplace(const int* __restrict__ src,
                                                const int* __restrict__ dst,
                                                int* __restrict__ bucket_cur,
                                                unsigned int* __restrict__ upairs) {
    __shared__ int h[NBUCK];
    __shared__ int base[NBUCK];
    int t = threadIdx.x;
    for (int i = t; i < NBUCK; i += 256) h[i] = 0;
    __syncthreads();
    int e0 = blockIdx.x * CHUNK;
    int e1 = e0 + CHUNK; if (e1 > NE) e1 = NE;
    for (int i = e0 + t; i < e1; i += 256) atomicAdd(&h[dst[i] >> BSHIFT], 1);
    __syncthreads();
    for (int i = t; i < NBUCK; i += 256) {
        int c = h[i];
        base[i] = c ? atomicAdd(&bucket_cur[i], c) : 0;
    }
    __syncthreads();
    for (int i = t; i < NBUCK; i += 256) h[i] = 0;
    __syncthreads();
    for (int i = e0 + t; i < e1; i += 256) {
        int d = dst[i];
        int b = d >> BSHIFT;
        int pos = base[b] + atomicAdd(&h[b], 1);
        upairs[pos] = ((unsigned)(d & (BSIZE - 1)) << 17) | (unsigned)src[i];
    }
}

__global__ __launch_bounds__(256) void k_csr(const int* __restrict__ bucket_start,
                                             const unsigned int* __restrict__ upairs,
                                             int* __restrict__ row_start,
                                             float* __restrict__ dinv,
                                             int* __restrict__ csr_src) {
    int b = blockIdx.x;
    int nbase = b << BSHIFT;
    int ncnt = NN - nbase; if (ncnt > BSIZE) ncnt = BSIZE;
    __shared__ int degl[BSIZE];
    __shared__ int curl[BSIZE];
    __shared__ int wsum[8];
    int t = threadIdx.x;
    int lane = t & 63, wave = t >> 6;
    for (int i = t; i < BSIZE; i += 256) degl[i] = 0;
    __syncthreads();
    int p0 = bucket_start[b], p1 = bucket_start[b + 1];
    for (int i = p0 + t; i < p1; i += 256) atomicAdd(&degl[upairs[i] >> 17], 1);
    __syncthreads();
    int vals[2], incs[2];
    #pragma unroll
    for (int k = 0; k < 2; ++k) {
        int seg = wave + k * 4;
        int v = degl[seg * 64 + lane];
        int inc = v;
        for (int off = 1; off < 64; off <<= 1) {
            int n = __shfl_up(inc, off, 64);
            if (lane >= off) inc += n;
        }
        vals[k] = v; incs[k] = inc;
        if (lane == 63) wsum[seg] = inc;
    }
    __syncthreads();
    #pragma unroll
    for (int k = 0; k < 2; ++k) {
        int seg = wave + k * 4;
        int soff = 0;
        for (int s = 0; s < 8; ++s) if (s < seg) soff += wsum[s];
        int idx = seg * 64 + lane;
        int rs = p0 + soff + incs[k] - vals[k];
        curl[idx] = rs;
        if (idx < ncnt) {
            row_start[nbase + idx] = rs;
            dinv[nbase + idx] = rsqrtf((float)(vals[k] + 1));
        }
    }
    __syncthreads();
    for (int i = p0 + t; i < p1; i += 256) {
        unsigned pk = upairs[i];
        int pos = atomicAdd(&curl[pk >> 17], 1);
        csr_src[pos] = (int)(pk & 0x1FFFFu);
    }
}

// ======== shared gather: sum of g[src] rows over a node's in-edges ========
__device__ __forceinline__ float gather_sum(const int* __restrict__ csr_src,
                                            const unsigned short* __restrict__ g,
                                            int start, int n, int lane) {
    float acc = 0.f;
    for (int base = 0; base < n; base += 64) {
        int m = n - base; if (m > 64) m = 64;
        int sv = (lane < m) ? csr_src[start + base + lane] : 0;
        int j = 0;
        for (; j + 8 <= m; j += 8) {
            int s0 = __shfl(sv, j),     s1 = __shfl(sv, j + 1);
            int s2 = __shfl(sv, j + 2), s3 = __shfl(sv, j + 3);
            int s4 = __shfl(sv, j + 4), s5 = __shfl(sv, j + 5);
            int s6 = __shfl(sv, j + 6), s7 = __shfl(sv, j + 7);
            float a0 = b2f(g[(size_t)s0 * HH + lane]);
            float a1 = b2f(g[(size_t)s1 * HH + lane]);
            float a2 = b2f(g[(size_t)s2 * HH + lane]);
            float a3 = b2f(g[(size_t)s3 * HH + lane]);
            float a4 = b2f(g[(size_t)s4 * HH + lane]);
            float a5 = b2f(g[(size_t)s5 * HH + lane]);
            float a6 = b2f(g[(size_t)s6 * HH + lane]);
            float a7 = b2f(g[(size_t)s7 * HH + lane]);
            acc += a0; acc += a1; acc += a2; acc += a3;
            acc += a4; acc += a5; acc += a6; acc += a7;
        }
        for (; j < m; ++j) {
            int s = __shfl(sv, j);
            acc += b2f(g[(size_t)s * HH + lane]);
        }
    }
    return acc;
}

// ===== fused embed + GEMM0: g0 = dinv * (relu(x@We+be) @ W0), h only in LDS =====
#define SXE 136
#define SH 72
__global__ __launch_bounds__(256) void k_embed_gemm0(const float* __restrict__ x,
                                                     const float* __restrict__ Wemb,
                                                     const float* __restrict__ bemb,
                                                     const float* __restrict__ W0,
                                                     const float* __restrict__ dinv,
                                                     unsigned short* __restrict__ gout) {
    __shared__ __align__(16) unsigned short Xl[64 * SXE];   // 17.4 KB (reused as h-tile)
    __shared__ __align__(16) unsigned short WeT[64 * SXE];  // 17.4 KB
    __shared__ __align__(16) unsigned short W0t[64 * SH];   // 9.2 KB
    __shared__ float bl[64];
    int t = threadIdx.x;
    for (int i = t; i < 64 * SXE; i += 256) { Xl[i] = 0; WeT[i] = 0; }
    if (t < 64) bl[t] = bemb[t];
    for (int i = t; i < HH * HH; i += 256) { int k = i >> 6, n = i & 63; W0t[n * SH + k] = f2b(W0[i]); }
    __syncthreads();
    int row0 = blockIdx.x * 64;
    for (int i = t; i < 64 * FIN; i += 256) {
        int r = i / FIN, c = i - r * FIN;
        int row = row0 + r;
        if (row < NN) Xl[r * SXE + c] = f2b(x[(size_t)row * FIN + c]);
    }
    for (int i = t; i < FIN * HH; i += 256) {
        int k = i >> 6, n = i & 63;
        WeT[n * SXE + k] = f2b(Wemb[i]);
    }
    __syncthreads();

    int w = t >> 6, l = t & 63;
    int m16 = l & 15, g4 = l >> 4;
    f32x4 acc[4] = {{0,0,0,0},{0,0,0,0},{0,0,0,0},{0,0,0,0}};
    const unsigned short* Arow = &Xl[(w * 16 + m16) * SXE + g4 * 8];
    #pragma unroll
    for (int kk = 0; kk < 4; ++kk) {
        short8 a = *reinterpret_cast<const short8*>(Arow + kk * 32);
        #pragma unroll
        for (int c = 0; c < 4; ++c) {
            short8 bfr = *reinterpret_cast<const short8*>(&WeT[(c * 16 + m16) * SXE + g4 * 8 + kk * 32]);
            acc[c] = __builtin_amdgcn_mfma_f32_16x16x32_bf16(a, bfr, acc[c], 0, 0, 0);
        }
    }
    __syncthreads();                 // all waves done reading Xl
    unsigned short* hl = Xl;         // h-tile aliased onto Xl, stride SH
    #pragma unroll
    for (int c = 0; c < 4; ++c) {
        int col = c * 16 + m16;
        float bb = bl[col];
        #pragma unroll
        for (int r = 0; r < 4; ++r) {
            int rr = w * 16 + g4 * 4 + r;
            hl[rr * SH + col] = f2b(relu_f(acc[c][r] + bb));
        }
    }
    __syncthreads();
    // MFMA2: g0 = dinv * (h @ W0)
    f32x4 acc2[4] = {{0,0,0,0},{0,0,0,0},{0,0,0,0},{0,0,0,0}};
    const unsigned short* Hrow = &hl[(w * 16 + m16) * SH + g4 * 8];
    #pragma unroll
    for (int kk = 0; kk < 2; ++kk) {
        short8 a = *reinterpret_cast<const short8*>(Hrow + kk * 32);
        #pragma unroll
        for (int c = 0; c < 4; ++c) {
            short8 bfr = *reinterpret_cast<const short8*>(&W0t[(c * 16 + m16) * SH + g4 * 8 + kk * 32]);
            acc2[c] = __builtin_amdgcn_mfma_f32_16x16x32_bf16(a, bfr, acc2[c], 0, 0, 0);
        }
    }
    #pragma unroll
    for (int r = 0; r < 4; ++r) {
        int row = row0 + w * 16 + g4 * 4 + r;
        float dv = (row < NN) ? dinv[row] : 0.f;
        #pragma unroll
        for (int c = 0; c < 4; ++c) {
            int col = c * 16 + m16;
            if (row < NN) gout[(size_t)row * HH + col] = f2b(dv * acc2[c][r]);
        }
    }
}

// ===== fused agg + next-layer GEMM: g' = dinv * (relu(dinv*agg+b) @ Wnext) =====
__global__ __launch_bounds__(256) void k_agg_gemm(const int* __restrict__ row_start,
                                                  const int* __restrict__ csr_src,
                                                  const unsigned short* __restrict__ gin,
                                                  const float* __restrict__ dinv,
                                                  const float* __restrict__ bprev,
                                                  const float* __restrict__ Wnext,
                                                  unsigned short* __restrict__ gout) {
    __shared__ __align__(16) unsigned short hl[64 * SH];  // 9.2 KB
    __shared__ __align__(16) unsigned short Wt[64 * SH];  // 9.2 KB
    int t = threadIdx.x;
    for (int i = t; i < HH * HH; i += 256) { int k = i >> 6, n = i & 63; Wt[n * SH + k] = f2b(Wnext[i]); }
    int w = t >> 6, lane = t & 63;
    int row0 = blockIdx.x * 64;
    float b = bprev[lane];
    for (int i = 0; i < 16; ++i) {
        int v = row0 + w * 16 + i;
        float outv = 0.f;
        if (v < NN) {
            int st = row_start[v];
            int n = row_start[v + 1] - st;
            float acc = b2f(gin[(size_t)v * HH + lane]);    // self loop
            acc += gather_sum(csr_src, gin, st, n, lane);
            outv = relu_f(dinv[v] * acc + b);
        }
        hl[(w * 16 + i) * SH + lane] = f2b(outv);
    }
    __syncthreads();
    int m16 = lane & 15, g4 = lane >> 4;
    f32x4 acc2[4] = {{0,0,0,0},{0,0,0,0},{0,0,0,0},{0,0,0,0}};
    const unsigned short* Hrow = &hl[(w * 16 + m16) * SH + g4 * 8];
    #pragma unroll
    for (int kk = 0; kk < 2; ++kk) {
        short8 a = *reinterpret_cast<const short8*>(Hrow + kk * 32);
        #pragma unroll
        for (int c = 0; c < 4; ++c) {
            short8 bfr = *reinterpret_cast<const short8*>(&Wt[(c * 16 + m16) * SH + g4 * 8 + kk * 32]);
            acc2[c] = __builtin_amdgcn_mfma_f32_16x16x32_bf16(a, bfr, acc2[c], 0, 0, 0);
        }
    }
    #pragma unroll
    for (int r = 0; r < 4; ++r) {
        int row = row0 + w * 16 + g4 * 4 + r;
        float dv = (row < NN) ? dinv[row] : 0.f;
        #pragma unroll
        for (int c = 0; c < 4; ++c) {
            int col = c * 16 + m16;
            if (row < NN) gout[(size_t)row * HH + col] = f2b(dv * acc2[c][r]);
        }
    }
}

// ===== final layer: agg + finalize + per-graph partial pool (no atomics) =====
__global__ __launch_bounds__(256) void k_agg_pool(const int* __restrict__ row_start,
                                                  const int* __restrict__ csr_src,
                                                  const unsigned short* __restrict__ gin,
                                                  const float* __restrict__ dinv,
                                                  const float* __restrict__ bL,
                                                  const int* __restrict__ batch,
                                                  int* __restrict__ pgid,
                                                  float* __restrict__ psum,
                                                  float* __restrict__ pooled_fb) {
    int t = threadIdx.x, w = t >> 6, lane = t & 63;
    int row0 = blockIdx.x * 64;
    int widx = blockIdx.x * 4 + w;
    float b = bL[lane];
    int s = 0, cur = -1;
    float ps = 0.f;
    for (int i = 0; i < 16; ++i) {
        int v = row0 + w * 16 + i;
        if (v >= NN) break;
        int st = row_start[v];
        int n = row_start[v + 1] - st;
        float acc = b2f(gin[(size_t)v * HH + lane]);
        acc += gather_sum(csr_src, gin, st, n, lane);
        float outv = relu_f(dinv[v] * acc + b);
        int gb = batch[v];
        if (gb != cur) {
            if (cur >= 0) {
                if (s < MAXSEG) {
                    if (lane == 0) pgid[widx * MAXSEG + s] = cur;
                    psum[((size_t)widx * MAXSEG + s) * 64 + lane] = ps;
                    s++;
                } else {
                    unsafeAtomicAdd(&pooled_fb[cur * 64 + lane], ps);
                }
            }
            cur = gb; ps = 0.f;
        }
        ps += outv;
    }
    if (cur >= 0) {
        if (s < MAXSEG) {
            if (lane == 0) pgid[widx * MAXSEG + s] = cur;
            psum[((size_t)widx * MAXSEG + s) * 64 + lane] = ps;
            s++;
        } else {
            unsafeAtomicAdd(&pooled_fb[cur * 64 + lane], ps);
        }
    }
    for (; s < MAXSEG; ++s) if (lane == 0) pgid[widx * MAXSEG + s] = -1;
}

// ===== MLP readout: block per graph; reduce partials, then 64->64->32->1 =====
__global__ __launch_bounds__(256) void k_mlp(const int* __restrict__ pgid,
                                             const float* __restrict__ psum,
                                             const float* __restrict__ pooled_fb,
                                             const int* __restrict__ batch,
                                             const float* __restrict__ W1, const float* __restrict__ b1,
                                             const float* __restrict__ W2, const float* __restrict__ b2,
                                             const float* __restrict__ W3, const float* __restrict__ b3,
                                             float* __restrict__ out) {
    int g = blockIdx.x;
    int lo = 0, hi_s = NN;
    while (lo < hi_s) { int mid = (lo + hi_s) >> 1; if (batch[mid] < g) lo = mid + 1; else hi_s = mid; }
    int lo2 = lo, hi = NN;
    while (lo2 < hi) { int mid = (lo2 + hi) >> 1; if (batch[mid] < g + 1) lo2 = mid + 1; else hi = mid; }
    int lane = threadIdx.x & 63, wq = threadIdx.x >> 6;
    float s = 0.f;
    if (hi > lo) {
        int w0 = lo >> 4, w1 = (hi - 1) >> 4;
        for (int idx = w0 + wq; idx <= w1; idx += 4) {
            #pragma unroll
            for (int sl = 0; sl < MAXSEG; ++sl) {
                int gid = pgid[idx * MAXSEG + sl];
                if (gid == g) s += psum[((size_t)idx * MAXSEG + sl) * 64 + lane];
            }
        }
    }
    __shared__ float red[4][64];
    __shared__ float pv[64];
    __shared__ float tv[64];
    __shared__ float qv[32];
    red[wq][lane] = s;
    __syncthreads();
    int cnt = hi - lo;
    float invc = 1.f / (float)(cnt > 0 ? cnt : 1);
    if (threadIdx.x < 64) {
        pv[lane] = (red[0][lane] + red[1][lane] + red[2][lane] + red[3][lane]
                    + pooled_fb[g * 64 + lane]) * invc;
    }
    __syncthreads();
    if (threadIdx.x < 64) {
        int j = threadIdx.x;
        float s1 = b1[j];
        #pragma unroll
        for (int k = 0; k < 64; ++k) s1 = fmaf(pv[k], W1[k * 64 + j], s1);
        tv[j] = relu_f(s1);
    }
    __syncthreads();
    if (threadIdx.x < 32) {
        int j = threadIdx.x;
        float s2 = b2[j];
        #pragma unroll
        for (int k = 0; k < 64; ++k) s2 = fmaf(tv[k], W2[k * 32 + j], s2);
        qv[j] = relu_f(s2);
    }
    __syncthreads();
    if (threadIdx.x == 0) {
        float s3 = b3[0];
        #pragma unroll
        for (int k = 0; k < 32; ++k) s3 = fmaf(qv[k], W3[k], s3);
        out[g] = s3;
    }
}

extern "C" void kernel_launch(void* const* d_in, const int* in_sizes, int n_in,
                              void* d_out, int out_size, void* d_ws, size_t ws_size,
                              hipStream_t stream) {
    const float* x    = (const float*)d_in[0];
    const int*   ei   = (const int*)d_in[1];
    const int*   batch= (const int*)d_in[2];
    const float* Wemb = (const float*)d_in[3];
    const float* bemb = (const float*)d_in[4];
    const float* convW= (const float*)d_in[5];
    const float* convb= (const float*)d_in[6];
    const float* W1   = (const float*)d_in[7];
    const float* b1   = (const float*)d_in[8];
    const float* W2   = (const float*)d_in[9];
    const float* b2   = (const float*)d_in[10];
    const float* W3   = (const float*)d_in[11];
    const float* b3   = (const float*)d_in[12];
    float* out = (float*)d_out;

    auto alignup = [](size_t v) { return (v + 255) & ~(size_t)255; };
    char* p = (char*)d_ws;
    int*   row_start    = (int*)p;            p += alignup((size_t)(NN + 1) * 4);
    float* dinv         = (float*)p;          p += alignup((size_t)NN * 4);
    int*   bucket_cnt   = (int*)p;            p += alignup((size_t)NBUCK * 4);
    int*   bucket_start = (int*)p;            p += alignup((size_t)(NBUCK + 1) * 4);
    int*   bucket_cur   = (int*)p;            p += alignup((size_t)NBUCK * 4);
    int*   csr_src      = (int*)p;            p += alignup((size_t)NE * 4);
    unsigned short* gA  = (unsigned short*)p; p += alignup((size_t)NN * HH * 2);
    unsigned short* gB  = (unsigned short*)p; p += alignup((size_t)NN * HH * 2);
    int*   pgid         = (int*)p;            p += alignup((size_t)NWAVE * MAXSEG * 4);
    float* psum         = (float*)p;          p += alignup((size_t)NWAVE * MAXSEG * 64 * 4);
    float* pooled_fb    = (float*)p;          p += alignup((size_t)NG * 64 * 4);
    unsigned int* upairs = (unsigned int*)gA; // aliased: dead before k_embed_gemm0 writes gA

    const int* srcA = ei;
    const int* dstA = ei + NE;

    hipMemsetAsync(bucket_cnt, 0, (size_t)NBUCK * 4, stream);
    hipMemsetAsync(pooled_fb, 0, (size_t)NG * 64 * 4, stream);

    k_bcount<<<NPLACE, 256, 0, stream>>>(dstA, bucket_cnt);
    k_bscan<<<1, 256, 0, stream>>>(bucket_cnt, bucket_start, bucket_cur, row_start);
    k_bplace<<<NPLACE, 256, 0, stream>>>(srcA, dstA, bucket_cur, upairs);
    k_csr<<<NBUCK, 256, 0, stream>>>(bucket_start, upairs, row_start, dinv, csr_src);

    k_embed_gemm0<<<NBLK64, 256, 0, stream>>>(x, Wemb, bemb, convW + 0 * HH * HH, dinv, gA);
    k_agg_gemm<<<NBLK64, 256, 0, stream>>>(row_start, csr_src, gA, dinv,
                                           convb + 0 * HH, convW + 1 * HH * HH, gB);
    k_agg_gemm<<<NBLK64, 256, 0, stream>>>(row_start, csr_src, gB, dinv,
                                           convb + 1 * HH, convW + 2 * HH * HH, gA);
    k_agg_pool<<<NBLK64, 256, 0, stream>>>(row_start, csr_src, gA, dinv,
                                           convb + 2 * HH, batch, pgid, psum, pooled_fb);
    k_mlp<<<NG, 256, 0, stream>>>(pgid, psum, pooled_fb, batch,
                                  W1, b1, W2, b2, W3, b3, out);
}